// Round 7
// baseline (736.700 us; speedup 1.0000x reference)
//
#include <hip/hip_runtime.h>

#define S_ 2048
#define B_ 2
#define E_ 1024
#define H_ 16

typedef __bf16 bf16x8 __attribute__((ext_vector_type(8)));
typedef float f32x4 __attribute__((ext_vector_type(4)));
typedef unsigned short us4_t __attribute__((ext_vector_type(4)));
typedef unsigned u32x4 __attribute__((ext_vector_type(4)));
typedef unsigned u32x2 __attribute__((ext_vector_type(2)));
typedef short s16x4 __attribute__((ext_vector_type(4)));

static __device__ __forceinline__ unsigned short f2bf(float x) {
  union { float f; unsigned u; } v; v.f = x;
  unsigned r = v.u + 0x7fffu + ((v.u >> 16) & 1u);
  return (unsigned short)(r >> 16);
}
static __device__ __forceinline__ float bf2f(unsigned short h) {
  union { unsigned u; float f; } v; v.u = ((unsigned)h) << 16;
  return v.f;
}
static __device__ __forceinline__ unsigned pk_bf16(float a, float b) {
  unsigned r;
  asm("v_cvt_pk_bf16_f32 %0, %1, %2" : "=v"(r) : "v"(a), "v"(b));
  return r;
}

static __device__ __forceinline__ f32x4 mfma16(s16x4 a, s16x4 b, f32x4 c) {
#if __has_builtin(__builtin_amdgcn_mfma_f32_16x16x16bf16_1k)
  return __builtin_amdgcn_mfma_f32_16x16x16bf16_1k(a, b, c, 0, 0, 0);
#else
  asm("v_mfma_f32_16x16x16_bf16 %0, %1, %2, %0" : "+v"(c) : "v"(a), "v"(b));
  return c;
#endif
}

// ---------------- elementwise split / convert (vectorized) ----------------
__global__ void k_split2(const float* __restrict__ src, unsigned short* __restrict__ hi,
                         unsigned short* __restrict__ lo, int n4) {
  int i = blockIdx.x * blockDim.x + threadIdx.x;
  int st = gridDim.x * blockDim.x;
  for (; i < n4; i += st) {
    f32x4 x = ((const f32x4*)src)[i];
    us4_t h, lw;
    #pragma unroll
    for (int j = 0; j < 4; ++j) {
      unsigned short hh = f2bf(x[j]);
      h[j] = hh;
      lw[j] = f2bf(x[j] - bf2f(hh));
    }
    ((us4_t*)hi)[i] = h;
    ((us4_t*)lo)[i] = lw;
  }
}

__global__ void k_cvt(const float* __restrict__ src, unsigned short* __restrict__ dst, int n4) {
  int i = blockIdx.x * blockDim.x + threadIdx.x;
  int st = gridDim.x * blockDim.x;
  for (; i < n4; i += st) {
    f32x4 x = ((const f32x4*)src)[i];
    us4_t h;
    #pragma unroll
    for (int j = 0; j < 4; ++j) h[j] = f2bf(x[j]);
    ((us4_t*)dst)[i] = h;
  }
}

// ---------------- q/k projection: 3-term split GEMM ----------------
__launch_bounds__(256, 2)
__global__ void k_proj_qk(const unsigned short* __restrict__ qxh, const unsigned short* __restrict__ qxl,
                          const unsigned short* __restrict__ kxh, const unsigned short* __restrict__ kxl,
                          const unsigned short* __restrict__ wh, const unsigned short* __restrict__ wl,
                          const float* __restrict__ bias,
                          unsigned short* __restrict__ qh, unsigned short* __restrict__ ql,
                          unsigned short* __restrict__ kh, unsigned short* __restrict__ kl) {
  const int z = blockIdx.z;
  const unsigned short* Ah = z ? kxh : qxh;
  const unsigned short* Al = z ? kxl : qxl;
  const unsigned short* Bh = wh + (size_t)z * (1024 * 1024);
  const unsigned short* Bl = wl + (size_t)z * (1024 * 1024);
  unsigned short* Ch = z ? kh : qh;
  unsigned short* Cl = z ? kl : ql;
  const float* bia = bias + z * 1024;
  const float scale = z ? 1.0f : 0.125f;

  __shared__ unsigned short sAh[128][40], sAl[128][40], sBh[128][40], sBl[128][40];

  const int t = threadIdx.x;
  const int wid = t >> 6, l = t & 63, g = l >> 4, c = l & 15;
  const int wr = wid >> 1, wc = wid & 1;
  const int mb = blockIdx.x * 128, nb = blockIdx.y * 128;
  const int sr = t >> 1, sc = (t & 1) * 16;

  f32x4 acc[4][4] = {};

  for (int k0 = 0; k0 < 1024; k0 += 32) {
    __syncthreads();
    {
      const unsigned short* pah = Ah + (size_t)(mb + sr) * 1024 + k0 + sc;
      const unsigned short* pal = Al + (size_t)(mb + sr) * 1024 + k0 + sc;
      const unsigned short* pbh = Bh + (size_t)(nb + sr) * 1024 + k0 + sc;
      const unsigned short* pbl = Bl + (size_t)(nb + sr) * 1024 + k0 + sc;
      *(bf16x8*)&sAh[sr][sc]     = *(const bf16x8*)pah;
      *(bf16x8*)&sAh[sr][sc + 8] = *(const bf16x8*)(pah + 8);
      *(bf16x8*)&sAl[sr][sc]     = *(const bf16x8*)pal;
      *(bf16x8*)&sAl[sr][sc + 8] = *(const bf16x8*)(pal + 8);
      *(bf16x8*)&sBh[sr][sc]     = *(const bf16x8*)pbh;
      *(bf16x8*)&sBh[sr][sc + 8] = *(const bf16x8*)(pbh + 8);
      *(bf16x8*)&sBl[sr][sc]     = *(const bf16x8*)pbl;
      *(bf16x8*)&sBl[sr][sc + 8] = *(const bf16x8*)(pbl + 8);
    }
    __syncthreads();
    bf16x8 afh[4], afl[4], bfh[4], bfl[4];
    #pragma unroll
    for (int i = 0; i < 4; ++i) {
      afh[i] = *(const bf16x8*)&sAh[wr * 64 + i * 16 + c][g * 8];
      afl[i] = *(const bf16x8*)&sAl[wr * 64 + i * 16 + c][g * 8];
      bfh[i] = *(const bf16x8*)&sBh[wc * 64 + i * 16 + c][g * 8];
      bfl[i] = *(const bf16x8*)&sBl[wc * 64 + i * 16 + c][g * 8];
    }
    #pragma unroll
    for (int i = 0; i < 4; ++i)
      #pragma unroll
      for (int j = 0; j < 4; ++j) {
        acc[i][j] = __builtin_amdgcn_mfma_f32_16x16x32_bf16(afh[i], bfh[j], acc[i][j], 0, 0, 0);
        acc[i][j] = __builtin_amdgcn_mfma_f32_16x16x32_bf16(afh[i], bfl[j], acc[i][j], 0, 0, 0);
        acc[i][j] = __builtin_amdgcn_mfma_f32_16x16x32_bf16(afl[i], bfh[j], acc[i][j], 0, 0, 0);
      }
  }
  #pragma unroll
  for (int i = 0; i < 4; ++i)
    #pragma unroll
    for (int j = 0; j < 4; ++j)
      #pragma unroll
      for (int rr = 0; rr < 4; ++rr) {
        int m = mb + wr * 64 + i * 16 + 4 * g + rr;
        int n = nb + wc * 64 + j * 16 + c;
        float v = (acc[i][j][rr] + bia[n]) * scale;
        unsigned short hh = f2bf(v);
        size_t idx = (size_t)m * 1024 + n;
        Ch[idx] = hh;
        Cl[idx] = f2bf(v - bf2f(hh));
      }
}

// ---------------- v projection, writes V^T layout: VT[b][e'][j] ----------------
__launch_bounds__(256, 2)
__global__ void k_proj_v(const unsigned short* __restrict__ wv, const unsigned short* __restrict__ vx,
                         const float* __restrict__ bias, unsigned short* __restrict__ VT) {
  __shared__ unsigned short sA[128][40], sB[128][40];
  const int t = threadIdx.x;
  const int wid = t >> 6, l = t & 63, g = l >> 4, c = l & 15;
  const int wr = wid >> 1, wc = wid & 1;
  const int mb = blockIdx.x * 128;   // e' base
  const int nb = blockIdx.y * 128;   // n = b*2048 + j
  const int bb = nb >> 11;
  const int jb = nb & 2047;
  const int sr = t >> 1, sc = (t & 1) * 16;

  f32x4 acc[4][4] = {};
  for (int k0 = 0; k0 < 1024; k0 += 32) {
    __syncthreads();
    {
      const unsigned short* pa = wv + (size_t)(mb + sr) * 1024 + k0 + sc;
      const unsigned short* pbp = vx + ((size_t)(jb + sr) * 2 + bb) * 1024 + k0 + sc;
      *(bf16x8*)&sA[sr][sc]     = *(const bf16x8*)pa;
      *(bf16x8*)&sA[sr][sc + 8] = *(const bf16x8*)(pa + 8);
      *(bf16x8*)&sB[sr][sc]     = *(const bf16x8*)pbp;
      *(bf16x8*)&sB[sr][sc + 8] = *(const bf16x8*)(pbp + 8);
    }
    __syncthreads();
    bf16x8 af[4], bfr[4];
    #pragma unroll
    for (int i = 0; i < 4; ++i) {
      af[i]  = *(const bf16x8*)&sA[wr * 64 + i * 16 + c][g * 8];
      bfr[i] = *(const bf16x8*)&sB[wc * 64 + i * 16 + c][g * 8];
    }
    #pragma unroll
    for (int i = 0; i < 4; ++i)
      #pragma unroll
      for (int j = 0; j < 4; ++j)
        acc[i][j] = __builtin_amdgcn_mfma_f32_16x16x32_bf16(af[i], bfr[j], acc[i][j], 0, 0, 0);
  }
  #pragma unroll
  for (int i = 0; i < 4; ++i)
    #pragma unroll
    for (int j = 0; j < 4; ++j)
      #pragma unroll
      for (int rr = 0; rr < 4; ++rr) {
        int m = mb + wr * 64 + i * 16 + 4 * g + rr;
        int jj = jb + wc * 64 + j * 16 + c;
        float v = acc[i][j][rr] + bias[2048 + m];
        VT[(size_t)bb * (1024 * 2048) + (size_t)m * 2048 + jj] = f2bf(v);
      }
}

// ---------------- fused attention v3: 1 barrier/stage, no ping ----------------
// Block=(b,h,qt), 256 thr = 4 waves; wave ct owns cols ct*16 of each KVBLK=64.
// QK (16x16x32, swapped): acc@(g,c) = s[k=4g+rr][q=c]. That IS the B-fragment
// layout of mfma_f32_16x16x16_bf16 (lane(g,c): k=4g+j, col=c) -> PV B-operand
// comes directly from packed psc regs; A = V^T u32x2 from swizzled LDS.
// K/V staged via regs (distance-2) -> LDS dbuf; bias prefetched 1 stage ahead.
__launch_bounds__(256, 3)
__global__ void k_attn_pv(const unsigned short* __restrict__ qh, const unsigned short* __restrict__ ql,
                          const unsigned short* __restrict__ kh, const unsigned short* __restrict__ kl,
                          const unsigned short* __restrict__ VT, const float* __restrict__ posb,
                          float* __restrict__ attn, unsigned short* __restrict__ oc) {
  // qt-major XCD chunking: XCD x gets qt in [x*16, x*16+16), all (b,h) per qt
  // consecutive -> posb rows L2-hot across the 32 (b,h) blocks; K/V L3-hot.
  const int swz = (int)((blockIdx.x & 7) * 512 + (blockIdx.x >> 3));
  const int qt = swz >> 5;
  const int h = (swz >> 1) & 15;
  const int b = swz & 1;

  const int t = threadIdx.x;
  const int wid = t >> 6, l = t & 63, g = l >> 4, c = l & 15;
  const int ct = wid;

  __shared__ unsigned smem[12288];        // S_kh[2][2048] S_kl[2][2048] S_vt[2][2048]
  __shared__ float lds_red[4][16];
  unsigned* S_kh = smem;
  unsigned* S_kl = smem + 4096;
  unsigned* S_vt = smem + 8192;

  const size_t qoff = ((size_t)(qt * 16 + c) * 2 + b) * 1024 + h * 64 + g * 8;
  const bf16x8 qfh0 = *(const bf16x8*)(qh + qoff);
  const bf16x8 qfh1 = *(const bf16x8*)(qh + qoff + 32);
  const bf16x8 qfl0 = *(const bf16x8*)(ql + qoff);
  const bf16x8 qfl1 = *(const bf16x8*)(ql + qoff + 32);

  const unsigned short* khb = kh + (size_t)b * 1024 + h * 64;
  const unsigned short* klb = kl + (size_t)b * 1024 + h * 64;
  const unsigned short* vtb = VT + ((size_t)b * 1024 + h * 64) * 2048;
  const float* pbRow = posb + (size_t)b * S_ * S_ + (size_t)(qt * 16 + c) * S_ + ct * 16;

  // staging map: thread t -> row=t>>2, phys 16B-slots {2(t&3),2(t&3)+1};
  // source slot pre-swizzled (slot ^ (row&7)), LDS write linear (rule #21)
  const int srow = t >> 2;
  const int sw = srow & 7;
  const int s0 = ((t & 3) * 2) ^ sw;
  const int s1 = ((t & 3) * 2 + 1) ^ sw;

  // swizzled-read: logical 16B slot of a 128B row
  #define LDSRD(base, row, slot) \
    __builtin_bit_cast(bf16x8, *(const u32x4*)&(base)[(row) * 32 + ((((slot) ^ ((row) & 7))) * 4)])

  #define GLOAD(dst, stg) do { \
    const size_t rk_ = (size_t)((stg) * 64 + srow) * 2048; \
    const size_t rv_ = (size_t)srow * 2048 + (stg) * 64; \
    dst[0] = *(const u32x4*)(khb + rk_ + s0 * 8); \
    dst[1] = *(const u32x4*)(khb + rk_ + s1 * 8); \
    dst[2] = *(const u32x4*)(klb + rk_ + s0 * 8); \
    dst[3] = *(const u32x4*)(klb + rk_ + s1 * 8); \
    dst[4] = *(const u32x4*)(vtb + rv_ + s0 * 8); \
    dst[5] = *(const u32x4*)(vtb + rv_ + s1 * 8); \
  } while (0)

  #define SWRITE(src, buf) do { \
    *(u32x4*)&S_kh[(buf) * 2048 + t * 8]     = src[0]; \
    *(u32x4*)&S_kh[(buf) * 2048 + t * 8 + 4] = src[1]; \
    *(u32x4*)&S_kl[(buf) * 2048 + t * 8]     = src[2]; \
    *(u32x4*)&S_kl[(buf) * 2048 + t * 8 + 4] = src[3]; \
    *(u32x4*)&S_vt[(buf) * 2048 + t * 8]     = src[4]; \
    *(u32x4*)&S_vt[(buf) * 2048 + t * 8 + 4] = src[5]; \
  } while (0)

  u32x4 rg[2][6];
  f32x4 bias[2];
  unsigned psc0[32], psc1[32];
  float lsum = 0.f;
  f32x4 oacc[4] = {};

  // prologue: stage 0 -> LDS[0]; stage 1 -> rg[1]; bias(0) -> bias[0]
  GLOAD(rg[0], 0);
  SWRITE(rg[0], 0);
  GLOAD(rg[1], 1);
  bias[0] = *(const f32x4*)(pbRow + 4 * g);
  __syncthreads();

  #pragma unroll
  for (int st = 0; st < 32; ++st) {
    const int cur = st & 1;        // compile-time under full unroll
    // prefetch: loads for st+2 into just-freed rg[cur]; bias for st+1
    if (st < 30) GLOAD(rg[cur], st + 2);
    if (st < 31) bias[cur ^ 1] = *(const f32x4*)(pbRow + (st + 1) * 64 + 4 * g);

    // ---- QK (two独立 accumulator chains) ----
    {
      const int row = ct * 16 + c;
      const unsigned* kb = S_kh + cur * 2048;
      const unsigned* lb = S_kl + cur * 2048;
      bf16x8 kfh0 = LDSRD(kb, row, g);
      bf16x8 kfh1 = LDSRD(kb, row, 4 + g);
      bf16x8 kfl0 = LDSRD(lb, row, g);
      bf16x8 kfl1 = LDSRD(lb, row, 4 + g);
      f32x4 aA = {}, aB = {};
      aA = __builtin_amdgcn_mfma_f32_16x16x32_bf16(kfh0, qfh0, aA, 0, 0, 0);
      aB = __builtin_amdgcn_mfma_f32_16x16x32_bf16(kfh1, qfh1, aB, 0, 0, 0);
      aA = __builtin_amdgcn_mfma_f32_16x16x32_bf16(kfl0, qfh0, aA, 0, 0, 0);
      aB = __builtin_amdgcn_mfma_f32_16x16x32_bf16(kfl1, qfh1, aB, 0, 0, 0);
      aA = __builtin_amdgcn_mfma_f32_16x16x32_bf16(kfh0, qfl0, aA, 0, 0, 0);
      aB = __builtin_amdgcn_mfma_f32_16x16x32_bf16(kfh1, qfl1, aB, 0, 0, 0);
      float p0 = __expf(aA[0] + aB[0] + bias[cur][0]);
      float p1 = __expf(aA[1] + aB[1] + bias[cur][1]);
      float p2 = __expf(aA[2] + aB[2] + bias[cur][2]);
      float p3 = __expf(aA[3] + aB[3] + bias[cur][3]);
      lsum += (p0 + p1) + (p2 + p3);
      psc0[st] = pk_bf16(p0, p1);
      psc1[st] = pk_bf16(p2, p3);
    }

    // ---- PV: B directly from psc regs (K=16); A = V^T from LDS ----
    {
      u32x2 braw; braw[0] = psc0[st]; braw[1] = psc1[st];
      const s16x4 bfrag = __builtin_bit_cast(s16x4, braw);
      const unsigned* vb = S_vt + cur * 2048;
      #pragma unroll
      for (int dt = 0; dt < 4; ++dt) {
        const int row = dt * 16 + c;
        const int sl = (2 * ct + (g >> 1)) ^ (row & 7);
        u32x2 araw = *(const u32x2*)&vb[row * 32 + sl * 4 + 2 * (g & 1)];
        oacc[dt] = mfma16(__builtin_bit_cast(s16x4, araw), bfrag, oacc[dt]);
      }
    }

    // ---- write st+1's staged regs (loaded ~2 stages ago; counted vmcnt) ----
    if (st < 31) SWRITE(rg[cur ^ 1], cur ^ 1);
    __syncthreads();
  }

  // ---- softmax denominator ----
  lsum += __shfl_xor(lsum, 16, 64);
  lsum += __shfl_xor(lsum, 32, 64);
  if (l < 16) lds_red[wid][l] = lsum;
  __syncthreads();
  const float inv = 1.0f / ((lds_red[0][c] + lds_red[1][c]) + (lds_red[2][c] + lds_red[3][c]));

  // ---- cross-wave out reduce (ored aliases staging LDS, stride 68) ----
  float* ored = (float*)smem;            // [4 waves][16 q][68]
  #pragma unroll
  for (int dt = 0; dt < 4; ++dt) {
    f32x4 o = oacc[dt];
    o[0] *= inv; o[1] *= inv; o[2] *= inv; o[3] *= inv;
    *(f32x4*)&ored[(wid * 16 + c) * 68 + dt * 16 + 4 * g] = o;
  }
  __syncthreads();
  {
    const int q = t >> 4;
    const int d0 = (t & 15) * 4;
    f32x4 s0 = *(const f32x4*)&ored[(0 * 16 + q) * 68 + d0];
    f32x4 s1 = *(const f32x4*)&ored[(1 * 16 + q) * 68 + d0];
    f32x4 s2 = *(const f32x4*)&ored[(2 * 16 + q) * 68 + d0];
    f32x4 s3 = *(const f32x4*)&ored[(3 * 16 + q) * 68 + d0];
    f32x4 s;
    s[0] = (s0[0] + s1[0]) + (s2[0] + s3[0]);
    s[1] = (s0[1] + s1[1]) + (s2[1] + s3[1]);
    s[2] = (s0[2] + s1[2]) + (s2[2] + s3[2]);
    s[3] = (s0[3] + s1[3]) + (s2[3] + s3[3]);
    u32x2 pk;
    pk[0] = pk_bf16(s[0], s[1]);
    pk[1] = pk_bf16(s[2], s[3]);
    *(u32x2*)&oc[((size_t)(qt * 16 + q) * 2 + b) * 1024 + h * 64 + d0] = pk;
  }

  // ---- attn write (normalized) ----
  float* arow = attn + ((size_t)(b * 16 + h) * S_ + qt * 16 + c) * S_ + ct * 16;
  #pragma unroll
  for (int st = 0; st < 32; ++st) {
    f32x4 o;
    o[0] = __uint_as_float(psc0[st] << 16) * inv;
    o[1] = __uint_as_float(psc0[st] & 0xFFFF0000u) * inv;
    o[2] = __uint_as_float(psc1[st] << 16) * inv;
    o[3] = __uint_as_float(psc1[st] & 0xFFFF0000u) * inv;
    *(f32x4*)(arow + (size_t)st * 64 + 4 * g) = o;
  }
  #undef LDSRD
  #undef GLOAD
  #undef SWRITE
}

// ---------------- out projection ----------------
__launch_bounds__(256, 2)
__global__ void k_outproj(const unsigned short* __restrict__ oc, const unsigned short* __restrict__ ow,
                          const float* __restrict__ ob, float* __restrict__ out) {
  __shared__ unsigned short sA[128][40], sB[128][40];
  const int t = threadIdx.x;
  const int wid = t >> 6, l = t & 63, g = l >> 4, c = l & 15;
  const int wr = wid >> 1, wc = wid & 1;
  const int mb = blockIdx.x * 128, nb = blockIdx.y * 128;
  const int sr = t >> 1, sc = (t & 1) * 16;

  f32x4 acc[4][4] = {};
  for (int k0 = 0; k0 < 1024; k0 += 32) {
    __syncthreads();
    {
      const unsigned short* pa = oc + (size_t)(mb + sr) * 1024 + k0 + sc;
      const unsigned short* pbp = ow + (size_t)(nb + sr) * 1024 + k0 + sc;
      *(bf16x8*)&sA[sr][sc]     = *(const bf16x8*)pa;
      *(bf16x8*)&sA[sr][sc + 8] = *(const bf16x8*)(pa + 8);
      *(bf16x8*)&sB[sr][sc]     = *(const bf16x8*)pbp;
      *(bf16x8*)&sB[sr][sc + 8] = *(const bf16x8*)(pbp + 8);
    }
    __syncthreads();
    bf16x8 af[4], bfr[4];
    #pragma unroll
    for (int i = 0; i < 4; ++i) {
      af[i]  = *(const bf16x8*)&sA[wr * 64 + i * 16 + c][g * 8];
      bfr[i] = *(const bf16x8*)&sB[wc * 64 + i * 16 + c][g * 8];
    }
    #pragma unroll
    for (int i = 0; i < 4; ++i)
      #pragma unroll
      for (int j = 0; j < 4; ++j)
        acc[i][j] = __builtin_amdgcn_mfma_f32_16x16x32_bf16(af[i], bfr[j], acc[i][j], 0, 0, 0);
  }
  #pragma unroll
  for (int i = 0; i < 4; ++i)
    #pragma unroll
    for (int j = 0; j < 4; ++j)
      #pragma unroll
      for (int rr = 0; rr < 4; ++rr) {
        int m = mb + wr * 64 + i * 16 + 4 * g + rr;
        int n = nb + wc * 64 + j * 16 + c;
        out[(size_t)m * 1024 + n] = acc[i][j][rr] + ob[n];
      }
}

extern "C" void kernel_launch(void* const* d_in, const int* in_sizes, int n_in,
                              void* d_out, int out_size, void* d_ws, size_t ws_size,
                              hipStream_t stream) {
  (void)in_sizes; (void)n_in; (void)out_size; (void)ws_size;
  const float* query = (const float*)d_in[0];
  const float* keyi  = (const float*)d_in[1];
  const float* value = (const float*)d_in[2];
  const float* posb  = (const float*)d_in[3];
  const float* ipw   = (const float*)d_in[4];
  const float* ipb   = (const float*)d_in[5];
  const float* outw  = (const float*)d_in[6];
  const float* outb  = (const float*)d_in[7];
  float* out = (float*)d_out;
  float* attn = out + (size_t)S_ * B_ * E_;

  char* ws = (char*)d_ws;
  size_t off = 0;
  auto alloc = [&](size_t bytes) -> void* {
    void* p = ws + off;
    off += (bytes + 255) & ~(size_t)255;
    return p;
  };
  const size_t NTOK = (size_t)S_ * B_;  // 4096
  unsigned short* qxh = (unsigned short*)alloc(NTOK * 1024 * 2);
  unsigned short* qxl = (unsigned short*)alloc(NTOK * 1024 * 2);
  unsigned short* kxh = (unsigned short*)alloc(NTOK * 1024 * 2);
  unsigned short* kxl = (unsigned short*)alloc(NTOK * 1024 * 2);
  unsigned short* vx  = (unsigned short*)alloc(NTOK * 1024 * 2);
  unsigned short* wh  = (unsigned short*)alloc((size_t)2048 * 1024 * 2);
  unsigned short* wl  = (unsigned short*)alloc((size_t)2048 * 1024 * 2);
  unsigned short* wv  = (unsigned short*)alloc((size_t)1024 * 1024 * 2);
  unsigned short* ow  = (unsigned short*)alloc((size_t)1024 * 1024 * 2);
  unsigned short* qh  = (unsigned short*)alloc(NTOK * 1024 * 2);
  unsigned short* ql  = (unsigned short*)alloc(NTOK * 1024 * 2);
  unsigned short* kh  = (unsigned short*)alloc(NTOK * 1024 * 2);
  unsigned short* kl  = (unsigned short*)alloc(NTOK * 1024 * 2);
  unsigned short* VT  = (unsigned short*)alloc((size_t)2 * 1024 * 2048 * 2);
  unsigned short* oc  = (unsigned short*)alloc(NTOK * 1024 * 2);

  const int n1_4 = (int)(NTOK * 1024 / 4);
  k_split2<<<2048, 256, 0, stream>>>(query, qxh, qxl, n1_4);
  k_split2<<<2048, 256, 0, stream>>>(keyi, kxh, kxl, n1_4);
  k_cvt<<<2048, 256, 0, stream>>>(value, vx, n1_4);
  k_split2<<<1024, 256, 0, stream>>>(ipw, wh, wl, 2048 * 1024 / 4);
  k_cvt<<<512, 256, 0, stream>>>(ipw + 2048 * 1024, wv, 1024 * 1024 / 4);
  k_cvt<<<512, 256, 0, stream>>>(outw, ow, 1024 * 1024 / 4);

  k_proj_qk<<<dim3(32, 8, 2), 256, 0, stream>>>(qxh, qxl, kxh, kxl, wh, wl, ipb, qh, ql, kh, kl);
  k_proj_v<<<dim3(8, 32), 256, 0, stream>>>(wv, vx, ipb, VT);
  k_attn_pv<<<4096, 256, 0, stream>>>(qh, ql, kh, kl, VT, posb, attn, oc);
  k_outproj<<<dim3(32, 8), 256, 0, stream>>>(oc, ow, outb, out);
}

// Round 10
// 549.905 us; speedup vs baseline: 1.3397x; 1.3397x over previous
//
#include <hip/hip_runtime.h>

#define S_ 2048
#define B_ 2
#define E_ 1024
#define H_ 16

typedef __bf16 bf16x8 __attribute__((ext_vector_type(8)));
typedef float f32x4 __attribute__((ext_vector_type(4)));
typedef unsigned short us4_t __attribute__((ext_vector_type(4)));
typedef unsigned u32x4 __attribute__((ext_vector_type(4)));
typedef unsigned u32x2 __attribute__((ext_vector_type(2)));
typedef short s16x4 __attribute__((ext_vector_type(4)));

static __device__ __forceinline__ unsigned short f2bf(float x) {
  union { float f; unsigned u; } v; v.f = x;
  unsigned r = v.u + 0x7fffu + ((v.u >> 16) & 1u);
  return (unsigned short)(r >> 16);
}
static __device__ __forceinline__ float bf2f(unsigned short h) {
  union { unsigned u; float f; } v; v.u = ((unsigned)h) << 16;
  return v.f;
}
static __device__ __forceinline__ unsigned pk_bf16(float a, float b) {
  unsigned r;
  asm("v_cvt_pk_bf16_f32 %0, %1, %2" : "=v"(r) : "v"(a), "v"(b));
  return r;
}

static __device__ __forceinline__ f32x4 mfma16(s16x4 a, s16x4 b, f32x4 c) {
#if __has_builtin(__builtin_amdgcn_mfma_f32_16x16x16bf16_1k)
  return __builtin_amdgcn_mfma_f32_16x16x16bf16_1k(a, b, c, 0, 0, 0);
#else
  asm("v_mfma_f32_16x16x16_bf16 %0, %1, %2, %0" : "+v"(c) : "v"(a), "v"(b));
  return c;
#endif
}

// ---------------- elementwise split / convert (vectorized) ----------------
__global__ void k_split2(const float* __restrict__ src, unsigned short* __restrict__ hi,
                         unsigned short* __restrict__ lo, int n4) {
  int i = blockIdx.x * blockDim.x + threadIdx.x;
  int st = gridDim.x * blockDim.x;
  for (; i < n4; i += st) {
    f32x4 x = ((const f32x4*)src)[i];
    us4_t h, lw;
    #pragma unroll
    for (int j = 0; j < 4; ++j) {
      unsigned short hh = f2bf(x[j]);
      h[j] = hh;
      lw[j] = f2bf(x[j] - bf2f(hh));
    }
    ((us4_t*)hi)[i] = h;
    ((us4_t*)lo)[i] = lw;
  }
}

__global__ void k_cvt(const float* __restrict__ src, unsigned short* __restrict__ dst, int n4) {
  int i = blockIdx.x * blockDim.x + threadIdx.x;
  int st = gridDim.x * blockDim.x;
  for (; i < n4; i += st) {
    f32x4 x = ((const f32x4*)src)[i];
    us4_t h;
    #pragma unroll
    for (int j = 0; j < 4; ++j) h[j] = f2bf(x[j]);
    ((us4_t*)dst)[i] = h;
  }
}

// ---------------- q/k projection: 3-term split GEMM ----------------
__launch_bounds__(256, 2)
__global__ void k_proj_qk(const unsigned short* __restrict__ qxh, const unsigned short* __restrict__ qxl,
                          const unsigned short* __restrict__ kxh, const unsigned short* __restrict__ kxl,
                          const unsigned short* __restrict__ wh, const unsigned short* __restrict__ wl,
                          const float* __restrict__ bias,
                          unsigned short* __restrict__ qh, unsigned short* __restrict__ ql,
                          unsigned short* __restrict__ kh, unsigned short* __restrict__ kl) {
  const int z = blockIdx.z;
  const unsigned short* Ah = z ? kxh : qxh;
  const unsigned short* Al = z ? kxl : qxl;
  const unsigned short* Bh = wh + (size_t)z * (1024 * 1024);
  const unsigned short* Bl = wl + (size_t)z * (1024 * 1024);
  unsigned short* Ch = z ? kh : qh;
  unsigned short* Cl = z ? kl : ql;
  const float* bia = bias + z * 1024;
  const float scale = z ? 1.0f : 0.125f;

  __shared__ unsigned short sAh[128][40], sAl[128][40], sBh[128][40], sBl[128][40];

  const int t = threadIdx.x;
  const int wid = t >> 6, l = t & 63, g = l >> 4, c = l & 15;
  const int wr = wid >> 1, wc = wid & 1;
  const int mb = blockIdx.x * 128, nb = blockIdx.y * 128;
  const int sr = t >> 1, sc = (t & 1) * 16;

  f32x4 acc[4][4] = {};

  for (int k0 = 0; k0 < 1024; k0 += 32) {
    __syncthreads();
    {
      const unsigned short* pah = Ah + (size_t)(mb + sr) * 1024 + k0 + sc;
      const unsigned short* pal = Al + (size_t)(mb + sr) * 1024 + k0 + sc;
      const unsigned short* pbh = Bh + (size_t)(nb + sr) * 1024 + k0 + sc;
      const unsigned short* pbl = Bl + (size_t)(nb + sr) * 1024 + k0 + sc;
      *(bf16x8*)&sAh[sr][sc]     = *(const bf16x8*)pah;
      *(bf16x8*)&sAh[sr][sc + 8] = *(const bf16x8*)(pah + 8);
      *(bf16x8*)&sAl[sr][sc]     = *(const bf16x8*)pal;
      *(bf16x8*)&sAl[sr][sc + 8] = *(const bf16x8*)(pal + 8);
      *(bf16x8*)&sBh[sr][sc]     = *(const bf16x8*)pbh;
      *(bf16x8*)&sBh[sr][sc + 8] = *(const bf16x8*)(pbh + 8);
      *(bf16x8*)&sBl[sr][sc]     = *(const bf16x8*)pbl;
      *(bf16x8*)&sBl[sr][sc + 8] = *(const bf16x8*)(pbl + 8);
    }
    __syncthreads();
    bf16x8 afh[4], afl[4], bfh[4], bfl[4];
    #pragma unroll
    for (int i = 0; i < 4; ++i) {
      afh[i] = *(const bf16x8*)&sAh[wr * 64 + i * 16 + c][g * 8];
      afl[i] = *(const bf16x8*)&sAl[wr * 64 + i * 16 + c][g * 8];
      bfh[i] = *(const bf16x8*)&sBh[wc * 64 + i * 16 + c][g * 8];
      bfl[i] = *(const bf16x8*)&sBl[wc * 64 + i * 16 + c][g * 8];
    }
    #pragma unroll
    for (int i = 0; i < 4; ++i)
      #pragma unroll
      for (int j = 0; j < 4; ++j) {
        acc[i][j] = __builtin_amdgcn_mfma_f32_16x16x32_bf16(afh[i], bfh[j], acc[i][j], 0, 0, 0);
        acc[i][j] = __builtin_amdgcn_mfma_f32_16x16x32_bf16(afh[i], bfl[j], acc[i][j], 0, 0, 0);
        acc[i][j] = __builtin_amdgcn_mfma_f32_16x16x32_bf16(afl[i], bfh[j], acc[i][j], 0, 0, 0);
      }
  }
  #pragma unroll
  for (int i = 0; i < 4; ++i)
    #pragma unroll
    for (int j = 0; j < 4; ++j)
      #pragma unroll
      for (int rr = 0; rr < 4; ++rr) {
        int m = mb + wr * 64 + i * 16 + 4 * g + rr;
        int n = nb + wc * 64 + j * 16 + c;
        float v = (acc[i][j][rr] + bia[n]) * scale;
        unsigned short hh = f2bf(v);
        size_t idx = (size_t)m * 1024 + n;
        Ch[idx] = hh;
        Cl[idx] = f2bf(v - bf2f(hh));
      }
}

// ---------------- v projection, writes V^T layout: VT[b][e'][j] ----------------
__launch_bounds__(256, 2)
__global__ void k_proj_v(const unsigned short* __restrict__ wv, const unsigned short* __restrict__ vx,
                         const float* __restrict__ bias, unsigned short* __restrict__ VT) {
  __shared__ unsigned short sA[128][40], sB[128][40];
  const int t = threadIdx.x;
  const int wid = t >> 6, l = t & 63, g = l >> 4, c = l & 15;
  const int wr = wid >> 1, wc = wid & 1;
  const int mb = blockIdx.x * 128;   // e' base
  const int nb = blockIdx.y * 128;   // n = b*2048 + j
  const int bb = nb >> 11;
  const int jb = nb & 2047;
  const int sr = t >> 1, sc = (t & 1) * 16;

  f32x4 acc[4][4] = {};
  for (int k0 = 0; k0 < 1024; k0 += 32) {
    __syncthreads();
    {
      const unsigned short* pa = wv + (size_t)(mb + sr) * 1024 + k0 + sc;
      const unsigned short* pbp = vx + ((size_t)(jb + sr) * 2 + bb) * 1024 + k0 + sc;
      *(bf16x8*)&sA[sr][sc]     = *(const bf16x8*)pa;
      *(bf16x8*)&sA[sr][sc + 8] = *(const bf16x8*)(pa + 8);
      *(bf16x8*)&sB[sr][sc]     = *(const bf16x8*)pbp;
      *(bf16x8*)&sB[sr][sc + 8] = *(const bf16x8*)(pbp + 8);
    }
    __syncthreads();
    bf16x8 af[4], bfr[4];
    #pragma unroll
    for (int i = 0; i < 4; ++i) {
      af[i]  = *(const bf16x8*)&sA[wr * 64 + i * 16 + c][g * 8];
      bfr[i] = *(const bf16x8*)&sB[wc * 64 + i * 16 + c][g * 8];
    }
    #pragma unroll
    for (int i = 0; i < 4; ++i)
      #pragma unroll
      for (int j = 0; j < 4; ++j)
        acc[i][j] = __builtin_amdgcn_mfma_f32_16x16x32_bf16(af[i], bfr[j], acc[i][j], 0, 0, 0);
  }
  #pragma unroll
  for (int i = 0; i < 4; ++i)
    #pragma unroll
    for (int j = 0; j < 4; ++j)
      #pragma unroll
      for (int rr = 0; rr < 4; ++rr) {
        int m = mb + wr * 64 + i * 16 + 4 * g + rr;
        int jj = jb + wc * 64 + j * 16 + c;
        float v = acc[i][j][rr] + bias[2048 + m];
        VT[(size_t)bb * (1024 * 2048) + (size_t)m * 2048 + jj] = f2bf(v);
      }
}

// ---------------- fused attention v4: R7 pipeline + R6 h-major swizzle ----------------
// Block=(b,h,qt), 256 thr = 4 waves; wave ct owns cols ct*16 of each KVBLK=64.
// QK (16x16x32, swapped): acc@(g,c) = s[k=4g+rr][q=c] == B-fragment layout of
// mfma_f32_16x16x16_bf16 -> PV B-operand direct from packed psc regs (no ping,
// 1 barrier/stage); A = V^T u32x2 from swizzled LDS.
// K/V staged via regs (distance-2) -> LDS dbuf; bias prefetched 1 stage ahead.
__launch_bounds__(256, 3)
__global__ void k_attn_pv(const unsigned short* __restrict__ qh, const unsigned short* __restrict__ ql,
                          const unsigned short* __restrict__ kh, const unsigned short* __restrict__ kl,
                          const unsigned short* __restrict__ VT, const float* __restrict__ posb,
                          float* __restrict__ attn, unsigned short* __restrict__ oc) {
  // h-major XCD chunking (R6): each XCD serves 2 heads -> K/V working set ~6MB,
  // L2/L3-friendly. (qt-major variant measured 5.7x more HBM fetch - do not use.)
  const int swz = (int)((blockIdx.x & 7) * 512 + (blockIdx.x >> 3));
  const int h = swz >> 8;
  const int b = (swz >> 7) & 1;
  const int qt = swz & 127;

  const int t = threadIdx.x;
  const int wid = t >> 6, l = t & 63, g = l >> 4, c = l & 15;
  const int ct = wid;

  __shared__ unsigned smem[12288];        // S_kh[2][2048] S_kl[2][2048] S_vt[2][2048]
  __shared__ float lds_red[4][16];
  unsigned* S_kh = smem;
  unsigned* S_kl = smem + 4096;
  unsigned* S_vt = smem + 8192;

  const size_t qoff = ((size_t)(qt * 16 + c) * 2 + b) * 1024 + h * 64 + g * 8;
  const bf16x8 qfh0 = *(const bf16x8*)(qh + qoff);
  const bf16x8 qfh1 = *(const bf16x8*)(qh + qoff + 32);
  const bf16x8 qfl0 = *(const bf16x8*)(ql + qoff);
  const bf16x8 qfl1 = *(const bf16x8*)(ql + qoff + 32);

  const unsigned short* khb = kh + (size_t)b * 1024 + h * 64;
  const unsigned short* klb = kl + (size_t)b * 1024 + h * 64;
  const unsigned short* vtb = VT + ((size_t)b * 1024 + h * 64) * 2048;
  const float* pbRow = posb + (size_t)b * S_ * S_ + (size_t)(qt * 16 + c) * S_ + ct * 16;

  // staging map: thread t -> row=t>>2, phys 16B-slots {2(t&3),2(t&3)+1};
  // source slot pre-swizzled (slot ^ (row&7)), LDS write linear (rule #21)
  const int srow = t >> 2;
  const int sw = srow & 7;
  const int s0 = ((t & 3) * 2) ^ sw;
  const int s1 = ((t & 3) * 2 + 1) ^ sw;

  // swizzled-read: logical 16B slot of a 128B row
  #define LDSRD(base, row, slot) \
    __builtin_bit_cast(bf16x8, *(const u32x4*)&(base)[(row) * 32 + ((((slot) ^ ((row) & 7))) * 4)])

  #define GLOAD(dst, stg) do { \
    const size_t rk_ = (size_t)((stg) * 64 + srow) * 2048; \
    const size_t rv_ = (size_t)srow * 2048 + (stg) * 64; \
    dst[0] = *(const u32x4*)(khb + rk_ + s0 * 8); \
    dst[1] = *(const u32x4*)(khb + rk_ + s1 * 8); \
    dst[2] = *(const u32x4*)(klb + rk_ + s0 * 8); \
    dst[3] = *(const u32x4*)(klb + rk_ + s1 * 8); \
    dst[4] = *(const u32x4*)(vtb + rv_ + s0 * 8); \
    dst[5] = *(const u32x4*)(vtb + rv_ + s1 * 8); \
  } while (0)

  #define SWRITE(src, buf) do { \
    *(u32x4*)&S_kh[(buf) * 2048 + t * 8]     = src[0]; \
    *(u32x4*)&S_kh[(buf) * 2048 + t * 8 + 4] = src[1]; \
    *(u32x4*)&S_kl[(buf) * 2048 + t * 8]     = src[2]; \
    *(u32x4*)&S_kl[(buf) * 2048 + t * 8 + 4] = src[3]; \
    *(u32x4*)&S_vt[(buf) * 2048 + t * 8]     = src[4]; \
    *(u32x4*)&S_vt[(buf) * 2048 + t * 8 + 4] = src[5]; \
  } while (0)

  u32x4 rg[2][6];
  f32x4 bias[2];
  unsigned psc0[32], psc1[32];
  float lsum = 0.f;
  f32x4 oacc[4] = {};

  // prologue: stage 0 -> LDS[0]; stage 1 -> rg[1]; bias(0) -> bias[0]
  GLOAD(rg[0], 0);
  SWRITE(rg[0], 0);
  GLOAD(rg[1], 1);
  bias[0] = *(const f32x4*)(pbRow + 4 * g);
  __syncthreads();

  #pragma unroll
  for (int st = 0; st < 32; ++st) {
    const int cur = st & 1;        // compile-time under full unroll
    // prefetch: loads for st+2 into just-freed rg[cur]; bias for st+1
    if (st < 30) GLOAD(rg[cur], st + 2);
    if (st < 31) bias[cur ^ 1] = *(const f32x4*)(pbRow + (st + 1) * 64 + 4 * g);

    // ---- QK (two independent accumulator chains) ----
    {
      const int row = ct * 16 + c;
      const unsigned* kb = S_kh + cur * 2048;
      const unsigned* lb = S_kl + cur * 2048;
      bf16x8 kfh0 = LDSRD(kb, row, g);
      bf16x8 kfh1 = LDSRD(kb, row, 4 + g);
      bf16x8 kfl0 = LDSRD(lb, row, g);
      bf16x8 kfl1 = LDSRD(lb, row, 4 + g);
      f32x4 aA = {}, aB = {};
      aA = __builtin_amdgcn_mfma_f32_16x16x32_bf16(kfh0, qfh0, aA, 0, 0, 0);
      aB = __builtin_amdgcn_mfma_f32_16x16x32_bf16(kfh1, qfh1, aB, 0, 0, 0);
      aA = __builtin_amdgcn_mfma_f32_16x16x32_bf16(kfl0, qfh0, aA, 0, 0, 0);
      aB = __builtin_amdgcn_mfma_f32_16x16x32_bf16(kfl1, qfh1, aB, 0, 0, 0);
      aA = __builtin_amdgcn_mfma_f32_16x16x32_bf16(kfh0, qfl0, aA, 0, 0, 0);
      aB = __builtin_amdgcn_mfma_f32_16x16x32_bf16(kfh1, qfl1, aB, 0, 0, 0);
      float p0 = __expf(aA[0] + aB[0] + bias[cur][0]);
      float p1 = __expf(aA[1] + aB[1] + bias[cur][1]);
      float p2 = __expf(aA[2] + aB[2] + bias[cur][2]);
      float p3 = __expf(aA[3] + aB[3] + bias[cur][3]);
      lsum += (p0 + p1) + (p2 + p3);
      psc0[st] = pk_bf16(p0, p1);
      psc1[st] = pk_bf16(p2, p3);
    }

    // ---- PV: B directly from psc regs (K=16); A = V^T from LDS ----
    {
      u32x2 braw; braw[0] = psc0[st]; braw[1] = psc1[st];
      const s16x4 bfrag = __builtin_bit_cast(s16x4, braw);
      const unsigned* vb = S_vt + cur * 2048;
      #pragma unroll
      for (int dt = 0; dt < 4; ++dt) {
        const int row = dt * 16 + c;
        const int sl = (2 * ct + (g >> 1)) ^ (row & 7);
        u32x2 araw = *(const u32x2*)&vb[row * 32 + sl * 4 + 2 * (g & 1)];
        oacc[dt] = mfma16(__builtin_bit_cast(s16x4, araw), bfrag, oacc[dt]);
      }
    }

    // ---- write st+1's staged regs (loaded ~2 stages ago; counted vmcnt) ----
    if (st < 31) SWRITE(rg[cur ^ 1], cur ^ 1);
    __syncthreads();
  }

  // ---- softmax denominator ----
  lsum += __shfl_xor(lsum, 16, 64);
  lsum += __shfl_xor(lsum, 32, 64);
  if (l < 16) lds_red[wid][l] = lsum;
  __syncthreads();
  const float inv = 1.0f / ((lds_red[0][c] + lds_red[1][c]) + (lds_red[2][c] + lds_red[3][c]));

  // ---- cross-wave out reduce (ored aliases staging LDS, stride 68) ----
  float* ored = (float*)smem;            // [4 waves][16 q][68]
  #pragma unroll
  for (int dt = 0; dt < 4; ++dt) {
    f32x4 o = oacc[dt];
    o[0] *= inv; o[1] *= inv; o[2] *= inv; o[3] *= inv;
    *(f32x4*)&ored[(wid * 16 + c) * 68 + dt * 16 + 4 * g] = o;
  }
  __syncthreads();
  {
    const int q = t >> 4;
    const int d0 = (t & 15) * 4;
    f32x4 s0 = *(const f32x4*)&ored[(0 * 16 + q) * 68 + d0];
    f32x4 s1 = *(const f32x4*)&ored[(1 * 16 + q) * 68 + d0];
    f32x4 s2 = *(const f32x4*)&ored[(2 * 16 + q) * 68 + d0];
    f32x4 s3 = *(const f32x4*)&ored[(3 * 16 + q) * 68 + d0];
    f32x4 s;
    s[0] = (s0[0] + s1[0]) + (s2[0] + s3[0]);
    s[1] = (s0[1] + s1[1]) + (s2[1] + s3[1]);
    s[2] = (s0[2] + s1[2]) + (s2[2] + s3[2]);
    s[3] = (s0[3] + s1[3]) + (s2[3] + s3[3]);
    u32x2 pk;
    pk[0] = pk_bf16(s[0], s[1]);
    pk[1] = pk_bf16(s[2], s[3]);
    *(u32x2*)&oc[((size_t)(qt * 16 + q) * 2 + b) * 1024 + h * 64 + d0] = pk;
  }

  // ---- attn write (normalized) ----
  float* arow = attn + ((size_t)(b * 16 + h) * S_ + qt * 16 + c) * S_ + ct * 16;
  #pragma unroll
  for (int st = 0; st < 32; ++st) {
    f32x4 o;
    o[0] = __uint_as_float(psc0[st] << 16) * inv;
    o[1] = __uint_as_float(psc0[st] & 0xFFFF0000u) * inv;
    o[2] = __uint_as_float(psc1[st] << 16) * inv;
    o[3] = __uint_as_float(psc1[st] & 0xFFFF0000u) * inv;
    *(f32x4*)(arow + (size_t)st * 64 + 4 * g) = o;
  }
  #undef LDSRD
  #undef GLOAD
  #undef SWRITE
}

// ---------------- out projection ----------------
__launch_bounds__(256, 2)
__global__ void k_outproj(const unsigned short* __restrict__ oc, const unsigned short* __restrict__ ow,
                          const float* __restrict__ ob, float* __restrict__ out) {
  __shared__ unsigned short sA[128][40], sB[128][40];
  const int t = threadIdx.x;
  const int wid = t >> 6, l = t & 63, g = l >> 4, c = l & 15;
  const int wr = wid >> 1, wc = wid & 1;
  const int mb = blockIdx.x * 128, nb = blockIdx.y * 128;
  const int sr = t >> 1, sc = (t & 1) * 16;

  f32x4 acc[4][4] = {};
  for (int k0 = 0; k0 < 1024; k0 += 32) {
    __syncthreads();
    {
      const unsigned short* pa = oc + (size_t)(mb + sr) * 1024 + k0 + sc;
      const unsigned short* pbp = ow + (size_t)(nb + sr) * 1024 + k0 + sc;
      *(bf16x8*)&sA[sr][sc]     = *(const bf16x8*)pa;
      *(bf16x8*)&sA[sr][sc + 8] = *(const bf16x8*)(pa + 8);
      *(bf16x8*)&sB[sr][sc]     = *(const bf16x8*)pbp;
      *(bf16x8*)&sB[sr][sc + 8] = *(const bf16x8*)(pbp + 8);
    }
    __syncthreads();
    bf16x8 af[4], bfr[4];
    #pragma unroll
    for (int i = 0; i < 4; ++i) {
      af[i]  = *(const bf16x8*)&sA[wr * 64 + i * 16 + c][g * 8];
      bfr[i] = *(const bf16x8*)&sB[wc * 64 + i * 16 + c][g * 8];
    }
    #pragma unroll
    for (int i = 0; i < 4; ++i)
      #pragma unroll
      for (int j = 0; j < 4; ++j)
        acc[i][j] = __builtin_amdgcn_mfma_f32_16x16x32_bf16(af[i], bfr[j], acc[i][j], 0, 0, 0);
  }
  #pragma unroll
  for (int i = 0; i < 4; ++i)
    #pragma unroll
    for (int j = 0; j < 4; ++j)
      #pragma unroll
      for (int rr = 0; rr < 4; ++rr) {
        int m = mb + wr * 64 + i * 16 + 4 * g + rr;
        int n = nb + wc * 64 + j * 16 + c;
        out[(size_t)m * 1024 + n] = acc[i][j][rr] + ob[n];
      }
}

extern "C" void kernel_launch(void* const* d_in, const int* in_sizes, int n_in,
                              void* d_out, int out_size, void* d_ws, size_t ws_size,
                              hipStream_t stream) {
  (void)in_sizes; (void)n_in; (void)out_size; (void)ws_size;
  const float* query = (const float*)d_in[0];
  const float* keyi  = (const float*)d_in[1];
  const float* value = (const float*)d_in[2];
  const float* posb  = (const float*)d_in[3];
  const float* ipw   = (const float*)d_in[4];
  const float* ipb   = (const float*)d_in[5];
  const float* outw  = (const float*)d_in[6];
  const float* outb  = (const float*)d_in[7];
  float* out = (float*)d_out;
  float* attn = out + (size_t)S_ * B_ * E_;

  char* ws = (char*)d_ws;
  size_t off = 0;
  auto alloc = [&](size_t bytes) -> void* {
    void* p = ws + off;
    off += (bytes + 255) & ~(size_t)255;
    return p;
  };
  const size_t NTOK = (size_t)S_ * B_;  // 4096
  unsigned short* qxh = (unsigned short*)alloc(NTOK * 1024 * 2);
  unsigned short* qxl = (unsigned short*)alloc(NTOK * 1024 * 2);
  unsigned short* kxh = (unsigned short*)alloc(NTOK * 1024 * 2);
  unsigned short* kxl = (unsigned short*)alloc(NTOK * 1024 * 2);
  unsigned short* vx  = (unsigned short*)alloc(NTOK * 1024 * 2);
  unsigned short* wh  = (unsigned short*)alloc((size_t)2048 * 1024 * 2);
  unsigned short* wl  = (unsigned short*)alloc((size_t)2048 * 1024 * 2);
  unsigned short* wv  = (unsigned short*)alloc((size_t)1024 * 1024 * 2);
  unsigned short* ow  = (unsigned short*)alloc((size_t)1024 * 1024 * 2);
  unsigned short* qh  = (unsigned short*)alloc(NTOK * 1024 * 2);
  unsigned short* ql  = (unsigned short*)alloc(NTOK * 1024 * 2);
  unsigned short* kh  = (unsigned short*)alloc(NTOK * 1024 * 2);
  unsigned short* kl  = (unsigned short*)alloc(NTOK * 1024 * 2);
  unsigned short* VT  = (unsigned short*)alloc((size_t)2 * 1024 * 2048 * 2);
  unsigned short* oc  = (unsigned short*)alloc(NTOK * 1024 * 2);

  const int n1_4 = (int)(NTOK * 1024 / 4);
  k_split2<<<2048, 256, 0, stream>>>(query, qxh, qxl, n1_4);
  k_split2<<<2048, 256, 0, stream>>>(keyi, kxh, kxl, n1_4);
  k_cvt<<<2048, 256, 0, stream>>>(value, vx, n1_4);
  k_split2<<<1024, 256, 0, stream>>>(ipw, wh, wl, 2048 * 1024 / 4);
  k_cvt<<<512, 256, 0, stream>>>(ipw + 2048 * 1024, wv, 1024 * 1024 / 4);
  k_cvt<<<512, 256, 0, stream>>>(outw, ow, 1024 * 1024 / 4);

  k_proj_qk<<<dim3(32, 8, 2), 256, 0, stream>>>(qxh, qxl, kxh, kxl, wh, wl, ipb, qh, ql, kh, kl);
  k_proj_v<<<dim3(8, 32), 256, 0, stream>>>(wv, vx, ipb, VT);
  k_attn_pv<<<4096, 256, 0, stream>>>(qh, ql, kh, kl, VT, posb, attn, oc);
  k_outproj<<<dim3(32, 8), 256, 0, stream>>>(oc, ow, outb, out);
}

// Round 12
// 469.413 us; speedup vs baseline: 1.5694x; 1.1715x over previous
//
#include <hip/hip_runtime.h>

#define S_ 2048
#define B_ 2
#define E_ 1024
#define H_ 16

typedef __bf16 bf16x8 __attribute__((ext_vector_type(8)));
typedef _Float16 f16x8 __attribute__((ext_vector_type(8)));
typedef _Float16 f16x4 __attribute__((ext_vector_type(4)));
typedef _Float16 f16x2 __attribute__((ext_vector_type(2)));
typedef float f32x4 __attribute__((ext_vector_type(4)));
typedef unsigned short us4_t __attribute__((ext_vector_type(4)));
typedef unsigned u32x4 __attribute__((ext_vector_type(4)));
typedef unsigned u32x2 __attribute__((ext_vector_type(2)));

static __device__ __forceinline__ unsigned short f2bf(float x) {
  union { float f; unsigned u; } v; v.f = x;
  unsigned r = v.u + 0x7fffu + ((v.u >> 16) & 1u);
  return (unsigned short)(r >> 16);
}
static __device__ __forceinline__ float bf2f(unsigned short h) {
  union { unsigned u; float f; } v; v.u = ((unsigned)h) << 16;
  return v.f;
}
static __device__ __forceinline__ unsigned short f2h(float x) {
  _Float16 h = (_Float16)x;
  return __builtin_bit_cast(unsigned short, h);
}
static __device__ __forceinline__ unsigned pk_f16(float a, float b) {
  auto r = __builtin_amdgcn_cvt_pkrtz(a, b);   // lo=a, hi=b (__fp16 x2)
  return __builtin_bit_cast(unsigned, r);
}
static __device__ __forceinline__ unsigned pk_bf16(float a, float b) {
  unsigned r;
  asm("v_cvt_pk_bf16_f32 %0, %1, %2" : "=v"(r) : "v"(a), "v"(b));
  return r;
}
static __device__ __forceinline__ f32x4 mfma16f(f16x4 a, f16x4 b, f32x4 c) {
#if __has_builtin(__builtin_amdgcn_mfma_f32_16x16x16f16)
  return __builtin_amdgcn_mfma_f32_16x16x16f16(a, b, c, 0, 0, 0);
#else
  asm("v_mfma_f32_16x16x16_f16 %0, %1, %2, %0" : "+v"(c) : "v"(a), "v"(b));
  return c;
#endif
}

// ---------------- elementwise split / convert (vectorized) ----------------
__global__ void k_split2(const float* __restrict__ src, unsigned short* __restrict__ hi,
                         unsigned short* __restrict__ lo, int n4) {
  int i = blockIdx.x * blockDim.x + threadIdx.x;
  int st = gridDim.x * blockDim.x;
  for (; i < n4; i += st) {
    f32x4 x = ((const f32x4*)src)[i];
    us4_t h, lw;
    #pragma unroll
    for (int j = 0; j < 4; ++j) {
      unsigned short hh = f2bf(x[j]);
      h[j] = hh;
      lw[j] = f2bf(x[j] - bf2f(hh));
    }
    ((us4_t*)hi)[i] = h;
    ((us4_t*)lo)[i] = lw;
  }
}

__global__ void k_cvt(const float* __restrict__ src, unsigned short* __restrict__ dst, int n4) {
  int i = blockIdx.x * blockDim.x + threadIdx.x;
  int st = gridDim.x * blockDim.x;
  for (; i < n4; i += st) {
    f32x4 x = ((const f32x4*)src)[i];
    us4_t h;
    #pragma unroll
    for (int j = 0; j < 4; ++j) h[j] = f2bf(x[j]);
    ((us4_t*)dst)[i] = h;
  }
}

// ---------------- q/k projection: 3-term split GEMM, fp16 output ----------------
__launch_bounds__(256, 2)
__global__ void k_proj_qk(const unsigned short* __restrict__ qxh, const unsigned short* __restrict__ qxl,
                          const unsigned short* __restrict__ kxh, const unsigned short* __restrict__ kxl,
                          const unsigned short* __restrict__ wh, const unsigned short* __restrict__ wl,
                          const float* __restrict__ bias,
                          unsigned short* __restrict__ qf, unsigned short* __restrict__ kf) {
  const int z = blockIdx.z;
  const unsigned short* Ah = z ? kxh : qxh;
  const unsigned short* Al = z ? kxl : qxl;
  const unsigned short* Bh = wh + (size_t)z * (1024 * 1024);
  const unsigned short* Bl = wl + (size_t)z * (1024 * 1024);
  unsigned short* Cq = z ? kf : qf;
  const float* bia = bias + z * 1024;
  const float scale = z ? 1.0f : 0.125f;

  __shared__ unsigned short sAh[128][40], sAl[128][40], sBh[128][40], sBl[128][40];

  const int t = threadIdx.x;
  const int wid = t >> 6, l = t & 63, g = l >> 4, c = l & 15;
  const int wr = wid >> 1, wc = wid & 1;
  const int mb = blockIdx.x * 128, nb = blockIdx.y * 128;
  const int sr = t >> 1, sc = (t & 1) * 16;

  f32x4 acc[4][4] = {};

  for (int k0 = 0; k0 < 1024; k0 += 32) {
    __syncthreads();
    {
      const unsigned short* pah = Ah + (size_t)(mb + sr) * 1024 + k0 + sc;
      const unsigned short* pal = Al + (size_t)(mb + sr) * 1024 + k0 + sc;
      const unsigned short* pbh = Bh + (size_t)(nb + sr) * 1024 + k0 + sc;
      const unsigned short* pbl = Bl + (size_t)(nb + sr) * 1024 + k0 + sc;
      *(bf16x8*)&sAh[sr][sc]     = *(const bf16x8*)pah;
      *(bf16x8*)&sAh[sr][sc + 8] = *(const bf16x8*)(pah + 8);
      *(bf16x8*)&sAl[sr][sc]     = *(const bf16x8*)pal;
      *(bf16x8*)&sAl[sr][sc + 8] = *(const bf16x8*)(pal + 8);
      *(bf16x8*)&sBh[sr][sc]     = *(const bf16x8*)pbh;
      *(bf16x8*)&sBh[sr][sc + 8] = *(const bf16x8*)(pbh + 8);
      *(bf16x8*)&sBl[sr][sc]     = *(const bf16x8*)pbl;
      *(bf16x8*)&sBl[sr][sc + 8] = *(const bf16x8*)(pbl + 8);
    }
    __syncthreads();
    bf16x8 afh[4], afl[4], bfh[4], bfl[4];
    #pragma unroll
    for (int i = 0; i < 4; ++i) {
      afh[i] = *(const bf16x8*)&sAh[wr * 64 + i * 16 + c][g * 8];
      afl[i] = *(const bf16x8*)&sAl[wr * 64 + i * 16 + c][g * 8];
      bfh[i] = *(const bf16x8*)&sBh[wc * 64 + i * 16 + c][g * 8];
      bfl[i] = *(const bf16x8*)&sBl[wc * 64 + i * 16 + c][g * 8];
    }
    #pragma unroll
    for (int i = 0; i < 4; ++i)
      #pragma unroll
      for (int j = 0; j < 4; ++j) {
        acc[i][j] = __builtin_amdgcn_mfma_f32_16x16x32_bf16(afh[i], bfh[j], acc[i][j], 0, 0, 0);
        acc[i][j] = __builtin_amdgcn_mfma_f32_16x16x32_bf16(afh[i], bfl[j], acc[i][j], 0, 0, 0);
        acc[i][j] = __builtin_amdgcn_mfma_f32_16x16x32_bf16(afl[i], bfh[j], acc[i][j], 0, 0, 0);
      }
  }
  #pragma unroll
  for (int i = 0; i < 4; ++i)
    #pragma unroll
    for (int j = 0; j < 4; ++j)
      #pragma unroll
      for (int rr = 0; rr < 4; ++rr) {
        int m = mb + wr * 64 + i * 16 + 4 * g + rr;
        int n = nb + wc * 64 + j * 16 + c;
        float v = (acc[i][j][rr] + bia[n]) * scale;
        Cq[(size_t)m * 1024 + n] = f2h(v);
      }
}

// ---------------- v projection, writes V^T (fp16): VT[b][e'][j] ----------------
__launch_bounds__(256, 2)
__global__ void k_proj_v(const unsigned short* __restrict__ wv, const unsigned short* __restrict__ vx,
                         const float* __restrict__ bias, unsigned short* __restrict__ VT) {
  __shared__ unsigned short sA[128][40], sB[128][40];
  const int t = threadIdx.x;
  const int wid = t >> 6, l = t & 63, g = l >> 4, c = l & 15;
  const int wr = wid >> 1, wc = wid & 1;
  const int mb = blockIdx.x * 128;   // e' base
  const int nb = blockIdx.y * 128;   // n = b*2048 + j
  const int bb = nb >> 11;
  const int jb = nb & 2047;
  const int sr = t >> 1, sc = (t & 1) * 16;

  f32x4 acc[4][4] = {};
  for (int k0 = 0; k0 < 1024; k0 += 32) {
    __syncthreads();
    {
      const unsigned short* pa = wv + (size_t)(mb + sr) * 1024 + k0 + sc;
      const unsigned short* pbp = vx + ((size_t)(jb + sr) * 2 + bb) * 1024 + k0 + sc;
      *(bf16x8*)&sA[sr][sc]     = *(const bf16x8*)pa;
      *(bf16x8*)&sA[sr][sc + 8] = *(const bf16x8*)(pa + 8);
      *(bf16x8*)&sB[sr][sc]     = *(const bf16x8*)pbp;
      *(bf16x8*)&sB[sr][sc + 8] = *(const bf16x8*)(pbp + 8);
    }
    __syncthreads();
    bf16x8 af[4], bfr[4];
    #pragma unroll
    for (int i = 0; i < 4; ++i) {
      af[i]  = *(const bf16x8*)&sA[wr * 64 + i * 16 + c][g * 8];
      bfr[i] = *(const bf16x8*)&sB[wc * 64 + i * 16 + c][g * 8];
    }
    #pragma unroll
    for (int i = 0; i < 4; ++i)
      #pragma unroll
      for (int j = 0; j < 4; ++j)
        acc[i][j] = __builtin_amdgcn_mfma_f32_16x16x32_bf16(af[i], bfr[j], acc[i][j], 0, 0, 0);
  }
  #pragma unroll
  for (int i = 0; i < 4; ++i)
    #pragma unroll
    for (int j = 0; j < 4; ++j)
      #pragma unroll
      for (int rr = 0; rr < 4; ++rr) {
        int m = mb + wr * 64 + i * 16 + 4 * g + rr;
        int jj = jb + wc * 64 + j * 16 + c;
        float v = acc[i][j][rr] + bias[2048 + m];
        VT[(size_t)bb * (1024 * 2048) + (size_t)m * 2048 + jj] = f2h(v);
      }
}

// ---------------- fused attention v5: fp16 Q/K/V/p, conflict-free staging ----------------
// Block=(b,h,qt), 256 thr = 4 waves; wave ct owns cols ct*16 of each KVBLK=64.
// QK: 2x mfma_f32_16x16x32_f16 (dims 0-31, 32-63). acc@(g,c)=s[k=4g+rr][q=c]
// == B-frag of 16x16x16 MFMA -> PV B direct from packed fp16 p regs;
// A = V^T f16x4 from swizzled LDS. p = exp(s-8) for fp16 range (cancels in norm).
// Staging: thread t writes LDS byte t*16 linearly (0-conflict); XOR swizzle is
// applied to the per-thread GLOBAL source slot (rule #21). Dist-2 reg prefetch.
__launch_bounds__(256, 4)
__global__ void k_attn_pv(const unsigned short* __restrict__ qf, const unsigned short* __restrict__ kf,
                          const unsigned short* __restrict__ VT, const float* __restrict__ posb,
                          float* __restrict__ attn, unsigned short* __restrict__ oc) {
  // h-major XCD chunking (R6-validated): ~6MB K/V working set per XCD.
  const int swz = (int)((blockIdx.x & 7) * 512 + (blockIdx.x >> 3));
  const int h = swz >> 8;
  const int b = (swz >> 7) & 1;
  const int qt = swz & 127;

  const int t = threadIdx.x;
  const int wid = t >> 6, l = t & 63, g = l >> 4, c = l & 15;
  const int ct = wid;

  __shared__ unsigned smem[8192];        // S_k[2][2048] S_v[2][2048] (u32)
  __shared__ float lds_red[4][16];
  unsigned* S_k = smem;
  unsigned* S_v = smem + 4096;

  const size_t qoff = ((size_t)(qt * 16 + c) * 2 + b) * 1024 + h * 64 + g * 8;
  const f16x8 qfr0 = *(const f16x8*)(qf + qoff);
  const f16x8 qfr1 = *(const f16x8*)(qf + qoff + 32);

  const unsigned short* kfb = kf + (size_t)b * 1024 + h * 64;
  const unsigned short* vtb = VT + ((size_t)b * 1024 + h * 64) * 2048;
  const float* pbRow = posb + (size_t)b * S_ * S_ + (size_t)(qt * 16 + c) * S_ + ct * 16;

  // staging map: thread t -> phys slot p=t&7 of row rb=t>>3 (and rb+32);
  // global source uses logical slot l = p ^ (rb&7) (pre-swizzled, rule #21)
  const int rb = t >> 3;                 // 0..31
  const int lsl = (t & 7) ^ (rb & 7);    // same for rb and rb+32 (32&7==0)

  // swizzled-read: logical 16B slot of a 128B row
  #define LDSRD(base, row, slot) \
    __builtin_bit_cast(f16x8, *(const u32x4*)&(base)[(row) * 32 + ((((slot) ^ ((row) & 7))) * 4)])

  #define GLOAD(dst, stg) do { \
    dst[0] = *(const u32x4*)(kfb + (size_t)((stg) * 64 + rb) * 2048 + lsl * 8); \
    dst[1] = *(const u32x4*)(kfb + (size_t)((stg) * 64 + rb + 32) * 2048 + lsl * 8); \
    dst[2] = *(const u32x4*)(vtb + (size_t)rb * 2048 + (stg) * 64 + lsl * 8); \
    dst[3] = *(const u32x4*)(vtb + (size_t)(rb + 32) * 2048 + (stg) * 64 + lsl * 8); \
  } while (0)

  // linear writes: lane-contiguous 16B -> zero bank conflicts
  #define SWRITE(src, buf) do { \
    *(u32x4*)&S_k[(buf) * 2048 + t * 4]        = src[0]; \
    *(u32x4*)&S_k[(buf) * 2048 + 1024 + t * 4] = src[1]; \
    *(u32x4*)&S_v[(buf) * 2048 + t * 4]        = src[2]; \
    *(u32x4*)&S_v[(buf) * 2048 + 1024 + t * 4] = src[3]; \
  } while (0)

  u32x4 rg[2][4];
  f32x4 bias[2];
  unsigned psc0[32], psc1[32];
  float lsum = 0.f;
  f32x4 oacc[4] = {};

  // prologue
  GLOAD(rg[0], 0);
  SWRITE(rg[0], 0);
  GLOAD(rg[1], 1);
  {
    f32x4 b0 = *(const f32x4*)(pbRow + 4 * g);
    bias[0][0] = b0[0] - 8.f; bias[0][1] = b0[1] - 8.f;
    bias[0][2] = b0[2] - 8.f; bias[0][3] = b0[3] - 8.f;
  }
  __syncthreads();

  #pragma unroll
  for (int st = 0; st < 32; ++st) {
    const int cur = st & 1;
    if (st < 30) GLOAD(rg[cur], st + 2);
    if (st < 31) {
      f32x4 bb = *(const f32x4*)(pbRow + (st + 1) * 64 + 4 * g);
      bias[cur ^ 1][0] = bb[0] - 8.f; bias[cur ^ 1][1] = bb[1] - 8.f;
      bias[cur ^ 1][2] = bb[2] - 8.f; bias[cur ^ 1][3] = bb[3] - 8.f;
    }

    // ---- QK: 2 MFMAs (dims 0-31, 32-63), independent chains ----
    {
      const int row = ct * 16 + c;
      const unsigned* kb = S_k + cur * 2048;
      f16x8 kfr0 = LDSRD(kb, row, g);
      f16x8 kfr1 = LDSRD(kb, row, 4 + g);
      f32x4 aA = {}, aB = {};
      aA = __builtin_amdgcn_mfma_f32_16x16x32_f16(kfr0, qfr0, aA, 0, 0, 0);
      aB = __builtin_amdgcn_mfma_f32_16x16x32_f16(kfr1, qfr1, aB, 0, 0, 0);
      float p0 = __expf(aA[0] + aB[0] + bias[cur][0]);
      float p1 = __expf(aA[1] + aB[1] + bias[cur][1]);
      float p2 = __expf(aA[2] + aB[2] + bias[cur][2]);
      float p3 = __expf(aA[3] + aB[3] + bias[cur][3]);
      lsum += (p0 + p1) + (p2 + p3);
      psc0[st] = pk_f16(p0, p1);
      psc1[st] = pk_f16(p2, p3);
    }

    // ---- PV: B from psc regs (fp16, K=16); A = V^T from LDS ----
    {
      u32x2 br; br[0] = psc0[st]; br[1] = psc1[st];
      const f16x4 bfrag = __builtin_bit_cast(f16x4, br);
      const unsigned* vb = S_v + cur * 2048;
      #pragma unroll
      for (int dt = 0; dt < 4; ++dt) {
        const int row = dt * 16 + c;
        const int sl = (2 * ct + (g >> 1)) ^ (row & 7);
        u32x2 ar = *(const u32x2*)&vb[row * 32 + sl * 4 + 2 * (g & 1)];
        oacc[dt] = mfma16f(__builtin_bit_cast(f16x4, ar), bfrag, oacc[dt]);
      }
    }

    if (st < 31) SWRITE(rg[cur ^ 1], cur ^ 1);
    __syncthreads();
  }

  // ---- softmax denominator ----
  lsum += __shfl_xor(lsum, 16, 64);
  lsum += __shfl_xor(lsum, 32, 64);
  if (l < 16) lds_red[wid][l] = lsum;
  __syncthreads();
  const float inv = 1.0f / ((lds_red[0][c] + lds_red[1][c]) + (lds_red[2][c] + lds_red[3][c]));

  // ---- cross-wave out reduce (ored aliases staging LDS, stride 68) ----
  float* ored = (float*)smem;            // [4 waves][16 q][68]
  #pragma unroll
  for (int dt = 0; dt < 4; ++dt) {
    f32x4 o = oacc[dt];
    o[0] *= inv; o[1] *= inv; o[2] *= inv; o[3] *= inv;
    *(f32x4*)&ored[(wid * 16 + c) * 68 + dt * 16 + 4 * g] = o;
  }
  __syncthreads();
  {
    const int q = t >> 4;
    const int d0 = (t & 15) * 4;
    f32x4 s0 = *(const f32x4*)&ored[(0 * 16 + q) * 68 + d0];
    f32x4 s1 = *(const f32x4*)&ored[(1 * 16 + q) * 68 + d0];
    f32x4 s2 = *(const f32x4*)&ored[(2 * 16 + q) * 68 + d0];
    f32x4 s3 = *(const f32x4*)&ored[(3 * 16 + q) * 68 + d0];
    f32x4 s;
    s[0] = (s0[0] + s1[0]) + (s2[0] + s3[0]);
    s[1] = (s0[1] + s1[1]) + (s2[1] + s3[1]);
    s[2] = (s0[2] + s1[2]) + (s2[2] + s3[2]);
    s[3] = (s0[3] + s1[3]) + (s2[3] + s3[3]);
    u32x2 pk;
    pk[0] = pk_bf16(s[0], s[1]);
    pk[1] = pk_bf16(s[2], s[3]);
    *(u32x2*)&oc[((size_t)(qt * 16 + q) * 2 + b) * 1024 + h * 64 + d0] = pk;
  }

  // ---- attn write (normalized), unpack fp16 p ----
  float* arow = attn + ((size_t)(b * 16 + h) * S_ + qt * 16 + c) * S_ + ct * 16;
  #pragma unroll
  for (int st = 0; st < 32; ++st) {
    f16x2 h0 = __builtin_bit_cast(f16x2, psc0[st]);
    f16x2 h1 = __builtin_bit_cast(f16x2, psc1[st]);
    f32x4 o;
    o[0] = (float)h0[0] * inv;
    o[1] = (float)h0[1] * inv;
    o[2] = (float)h1[0] * inv;
    o[3] = (float)h1[1] * inv;
    *(f32x4*)(arow + (size_t)st * 64 + 4 * g) = o;
  }
  #undef LDSRD
  #undef GLOAD
  #undef SWRITE
}

// ---------------- out projection ----------------
__launch_bounds__(256, 2)
__global__ void k_outproj(const unsigned short* __restrict__ oc, const unsigned short* __restrict__ ow,
                          const float* __restrict__ ob, float* __restrict__ out) {
  __shared__ unsigned short sA[128][40], sB[128][40];
  const int t = threadIdx.x;
  const int wid = t >> 6, l = t & 63, g = l >> 4, c = l & 15;
  const int wr = wid >> 1, wc = wid & 1;
  const int mb = blockIdx.x * 128, nb = blockIdx.y * 128;
  const int sr = t >> 1, sc = (t & 1) * 16;

  f32x4 acc[4][4] = {};
  for (int k0 = 0; k0 < 1024; k0 += 32) {
    __syncthreads();
    {
      const unsigned short* pa = oc + (size_t)(mb + sr) * 1024 + k0 + sc;
      const unsigned short* pbp = ow + (size_t)(nb + sr) * 1024 + k0 + sc;
      *(bf16x8*)&sA[sr][sc]     = *(const bf16x8*)pa;
      *(bf16x8*)&sA[sr][sc + 8] = *(const bf16x8*)(pa + 8);
      *(bf16x8*)&sB[sr][sc]     = *(const bf16x8*)pbp;
      *(bf16x8*)&sB[sr][sc + 8] = *(const bf16x8*)(pbp + 8);
    }
    __syncthreads();
    bf16x8 af[4], bfr[4];
    #pragma unroll
    for (int i = 0; i < 4; ++i) {
      af[i]  = *(const bf16x8*)&sA[wr * 64 + i * 16 + c][g * 8];
      bfr[i] = *(const bf16x8*)&sB[wc * 64 + i * 16 + c][g * 8];
    }
    #pragma unroll
    for (int i = 0; i < 4; ++i)
      #pragma unroll
      for (int j = 0; j < 4; ++j)
        acc[i][j] = __builtin_amdgcn_mfma_f32_16x16x32_bf16(af[i], bfr[j], acc[i][j], 0, 0, 0);
  }
  #pragma unroll
  for (int i = 0; i < 4; ++i)
    #pragma unroll
    for (int j = 0; j < 4; ++j)
      #pragma unroll
      for (int rr = 0; rr < 4; ++rr) {
        int m = mb + wr * 64 + i * 16 + 4 * g + rr;
        int n = nb + wc * 64 + j * 16 + c;
        out[(size_t)m * 1024 + n] = acc[i][j][rr] + ob[n];
      }
}

extern "C" void kernel_launch(void* const* d_in, const int* in_sizes, int n_in,
                              void* d_out, int out_size, void* d_ws, size_t ws_size,
                              hipStream_t stream) {
  (void)in_sizes; (void)n_in; (void)out_size; (void)ws_size;
  const float* query = (const float*)d_in[0];
  const float* keyi  = (const float*)d_in[1];
  const float* value = (const float*)d_in[2];
  const float* posb  = (const float*)d_in[3];
  const float* ipw   = (const float*)d_in[4];
  const float* ipb   = (const float*)d_in[5];
  const float* outw  = (const float*)d_in[6];
  const float* outb  = (const float*)d_in[7];
  float* out = (float*)d_out;
  float* attn = out + (size_t)S_ * B_ * E_;

  char* ws = (char*)d_ws;
  size_t off = 0;
  auto alloc = [&](size_t bytes) -> void* {
    void* p = ws + off;
    off += (bytes + 255) & ~(size_t)255;
    return p;
  };
  const size_t NTOK = (size_t)S_ * B_;  // 4096
  unsigned short* qxh = (unsigned short*)alloc(NTOK * 1024 * 2);
  unsigned short* qxl = (unsigned short*)alloc(NTOK * 1024 * 2);
  unsigned short* kxh = (unsigned short*)alloc(NTOK * 1024 * 2);
  unsigned short* kxl = (unsigned short*)alloc(NTOK * 1024 * 2);
  unsigned short* vx  = (unsigned short*)alloc(NTOK * 1024 * 2);
  unsigned short* wh  = (unsigned short*)alloc((size_t)2048 * 1024 * 2);
  unsigned short* wl  = (unsigned short*)alloc((size_t)2048 * 1024 * 2);
  unsigned short* wv  = (unsigned short*)alloc((size_t)1024 * 1024 * 2);
  unsigned short* ow  = (unsigned short*)alloc((size_t)1024 * 1024 * 2);
  unsigned short* qf  = (unsigned short*)alloc(NTOK * 1024 * 2);
  unsigned short* kf  = (unsigned short*)alloc(NTOK * 1024 * 2);
  unsigned short* VT  = (unsigned short*)alloc((size_t)2 * 1024 * 2048 * 2);
  unsigned short* oc  = (unsigned short*)alloc(NTOK * 1024 * 2);

  const int n1_4 = (int)(NTOK * 1024 / 4);
  k_split2<<<2048, 256, 0, stream>>>(query, qxh, qxl, n1_4);
  k_split2<<<2048, 256, 0, stream>>>(keyi, kxh, kxl, n1_4);
  k_cvt<<<2048, 256, 0, stream>>>(value, vx, n1_4);
  k_split2<<<1024, 256, 0, stream>>>(ipw, wh, wl, 2048 * 1024 / 4);
  k_cvt<<<512, 256, 0, stream>>>(ipw + 2048 * 1024, wv, 1024 * 1024 / 4);
  k_cvt<<<512, 256, 0, stream>>>(outw, ow, 1024 * 1024 / 4);

  k_proj_qk<<<dim3(32, 8, 2), 256, 0, stream>>>(qxh, qxl, kxh, kxl, wh, wl, ipb, qf, kf);
  k_proj_v<<<dim3(8, 32), 256, 0, stream>>>(wv, vx, ipb, VT);
  k_attn_pv<<<4096, 256, 0, stream>>>(qf, kf, VT, posb, attn, oc);
  k_outproj<<<dim3(32, 8), 256, 0, stream>>>(oc, ow, outb, out);
}

// Round 13
// 378.277 us; speedup vs baseline: 1.9475x; 1.2409x over previous
//
#include <hip/hip_runtime.h>

#define S_ 2048
#define B_ 2
#define E_ 1024
#define H_ 16

typedef _Float16 f16x8 __attribute__((ext_vector_type(8)));
typedef _Float16 f16x4 __attribute__((ext_vector_type(4)));
typedef _Float16 f16x2 __attribute__((ext_vector_type(2)));
typedef float f32x4 __attribute__((ext_vector_type(4)));
typedef unsigned short us4_t __attribute__((ext_vector_type(4)));
typedef unsigned u32x4 __attribute__((ext_vector_type(4)));
typedef unsigned u32x2 __attribute__((ext_vector_type(2)));

static __device__ __forceinline__ unsigned short f2h(float x) {
  _Float16 h = (_Float16)x;
  return __builtin_bit_cast(unsigned short, h);
}
static __device__ __forceinline__ unsigned pk_f16(float a, float b) {
  auto r = __builtin_amdgcn_cvt_pkrtz(a, b);   // lo=a, hi=b
  return __builtin_bit_cast(unsigned, r);
}

// ---------------- f32 -> fp16 convert (vectorized) ----------------
__global__ void k_cvth(const float* __restrict__ src, unsigned short* __restrict__ dst, int n4) {
  int i = blockIdx.x * blockDim.x + threadIdx.x;
  int st = gridDim.x * blockDim.x;
  for (; i < n4; i += st) {
    f32x4 x = ((const f32x4*)src)[i];
    us4_t h;
    #pragma unroll
    for (int j = 0; j < 4; ++j) h[j] = f2h(x[j]);
    ((us4_t*)dst)[i] = h;
  }
}

// ---------------- q/k projection: plain fp16 GEMM ----------------
// C[m][n] = sum_k A[m][k] * W[n][k]  (+bias) (*scale for q), fp16 out
__launch_bounds__(256, 2)
__global__ void k_proj_qk(const unsigned short* __restrict__ qx, const unsigned short* __restrict__ kx,
                          const unsigned short* __restrict__ wqk, const float* __restrict__ bias,
                          unsigned short* __restrict__ qf, unsigned short* __restrict__ kf) {
  const int z = blockIdx.z;
  const unsigned short* A = z ? kx : qx;
  const unsigned short* W = wqk + (size_t)z * (1024 * 1024);
  unsigned short* C = z ? kf : qf;
  const float* bia = bias + z * 1024;
  const float scale = z ? 1.0f : 0.125f;

  __shared__ unsigned short sA[128][40], sB[128][40];

  const int t = threadIdx.x;
  const int wid = t >> 6, l = t & 63, g = l >> 4, c = l & 15;
  const int wr = wid >> 1, wc = wid & 1;
  const int mb = blockIdx.x * 128, nb = blockIdx.y * 128;
  const int sr = t >> 1, sc = (t & 1) * 16;

  f32x4 acc[4][4] = {};

  for (int k0 = 0; k0 < 1024; k0 += 32) {
    __syncthreads();
    {
      const unsigned short* pa = A + (size_t)(mb + sr) * 1024 + k0 + sc;
      const unsigned short* pb = W + (size_t)(nb + sr) * 1024 + k0 + sc;
      *(f16x8*)&sA[sr][sc]     = *(const f16x8*)pa;
      *(f16x8*)&sA[sr][sc + 8] = *(const f16x8*)(pa + 8);
      *(f16x8*)&sB[sr][sc]     = *(const f16x8*)pb;
      *(f16x8*)&sB[sr][sc + 8] = *(const f16x8*)(pb + 8);
    }
    __syncthreads();
    f16x8 af[4], bf[4];
    #pragma unroll
    for (int i = 0; i < 4; ++i) {
      af[i] = *(const f16x8*)&sA[wr * 64 + i * 16 + c][g * 8];
      bf[i] = *(const f16x8*)&sB[wc * 64 + i * 16 + c][g * 8];
    }
    #pragma unroll
    for (int i = 0; i < 4; ++i)
      #pragma unroll
      for (int j = 0; j < 4; ++j)
        acc[i][j] = __builtin_amdgcn_mfma_f32_16x16x32_f16(af[i], bf[j], acc[i][j], 0, 0, 0);
  }
  #pragma unroll
  for (int i = 0; i < 4; ++i)
    #pragma unroll
    for (int j = 0; j < 4; ++j)
      #pragma unroll
      for (int rr = 0; rr < 4; ++rr) {
        int m = mb + wr * 64 + i * 16 + 4 * g + rr;
        int n = nb + wc * 64 + j * 16 + c;
        float v = (acc[i][j][rr] + bia[n]) * scale;
        C[(size_t)m * 1024 + n] = f2h(v);
      }
}

// ---------------- v projection (fp16), writes V^T: VT[b][e'][j] ----------------
__launch_bounds__(256, 2)
__global__ void k_proj_v(const unsigned short* __restrict__ wv, const unsigned short* __restrict__ vx,
                         const float* __restrict__ bias, unsigned short* __restrict__ VT) {
  __shared__ unsigned short sA[128][40], sB[128][40];
  const int t = threadIdx.x;
  const int wid = t >> 6, l = t & 63, g = l >> 4, c = l & 15;
  const int wr = wid >> 1, wc = wid & 1;
  const int mb = blockIdx.x * 128;   // e' base
  const int nb = blockIdx.y * 128;   // n = b*2048 + j
  const int bb = nb >> 11;
  const int jb = nb & 2047;
  const int sr = t >> 1, sc = (t & 1) * 16;

  f32x4 acc[4][4] = {};
  for (int k0 = 0; k0 < 1024; k0 += 32) {
    __syncthreads();
    {
      const unsigned short* pa = wv + (size_t)(mb + sr) * 1024 + k0 + sc;
      const unsigned short* pb = vx + ((size_t)(jb + sr) * 2 + bb) * 1024 + k0 + sc;
      *(f16x8*)&sA[sr][sc]     = *(const f16x8*)pa;
      *(f16x8*)&sA[sr][sc + 8] = *(const f16x8*)(pa + 8);
      *(f16x8*)&sB[sr][sc]     = *(const f16x8*)pb;
      *(f16x8*)&sB[sr][sc + 8] = *(const f16x8*)(pb + 8);
    }
    __syncthreads();
    f16x8 af[4], bf[4];
    #pragma unroll
    for (int i = 0; i < 4; ++i) {
      af[i] = *(const f16x8*)&sA[wr * 64 + i * 16 + c][g * 8];
      bf[i] = *(const f16x8*)&sB[wc * 64 + i * 16 + c][g * 8];
    }
    #pragma unroll
    for (int i = 0; i < 4; ++i)
      #pragma unroll
      for (int j = 0; j < 4; ++j)
        acc[i][j] = __builtin_amdgcn_mfma_f32_16x16x32_f16(af[i], bf[j], acc[i][j], 0, 0, 0);
  }
  #pragma unroll
  for (int i = 0; i < 4; ++i)
    #pragma unroll
    for (int j = 0; j < 4; ++j)
      #pragma unroll
      for (int rr = 0; rr < 4; ++rr) {
        int m = mb + wr * 64 + i * 16 + 4 * g + rr;
        int jj = jb + wc * 64 + j * 16 + c;
        float v = acc[i][j][rr] + bias[2048 + m];
        VT[(size_t)bb * (1024 * 2048) + (size_t)m * 2048 + jj] = f2h(v);
      }
}

// ---------------- fused attention v6: fp16 + distance-3 staging ----------------
// Block=(b,h,qt), 256 thr = 4 waves; wave ct owns cols ct*16 of each KVBLK=64.
// QK: 2x mfma_f32_16x16x32_f16. acc@(g,c)=s[k=4g+rr][q=c] == B-frag of K=16
// MFMA -> PV B direct from packed fp16 p regs; A = V^T from swizzled LDS.
// p = exp(s-8) (fp16-safe; cancels in norm). Staging: linear LDS writes
// (0-conflict), XOR swizzle folded into the GLOBAL source slot (rule #21).
// rg[3] slots: L(st+3) issued at st, SWRITTEN at st+2 -> ~2.5 stages of
// latency cover (dist-2 was the R10/R12 bottleneck).
__launch_bounds__(256, 3)
__global__ void k_attn_pv(const unsigned short* __restrict__ qf, const unsigned short* __restrict__ kf,
                          const unsigned short* __restrict__ VT, const float* __restrict__ posb,
                          float* __restrict__ attn, unsigned short* __restrict__ oc) {
  // h-major XCD chunking (R6-validated): ~3MB K/V working set per XCD.
  const int swz = (int)((blockIdx.x & 7) * 512 + (blockIdx.x >> 3));
  const int h = swz >> 8;
  const int b = (swz >> 7) & 1;
  const int qt = swz & 127;

  const int t = threadIdx.x;
  const int wid = t >> 6, l = t & 63, g = l >> 4, c = l & 15;
  const int ct = wid;

  __shared__ unsigned smem[8192];        // S_k[2][2048] S_v[2][2048] (u32)
  __shared__ float lds_red[4][16];
  unsigned* S_k = smem;
  unsigned* S_v = smem + 4096;

  const size_t qoff = ((size_t)(qt * 16 + c) * 2 + b) * 1024 + h * 64 + g * 8;
  const f16x8 qfr0 = *(const f16x8*)(qf + qoff);
  const f16x8 qfr1 = *(const f16x8*)(qf + qoff + 32);

  const unsigned short* kfb = kf + (size_t)b * 1024 + h * 64;
  const unsigned short* vtb = VT + ((size_t)b * 1024 + h * 64) * 2048;
  const float* pbRow = posb + (size_t)b * S_ * S_ + (size_t)(qt * 16 + c) * S_ + ct * 16;

  // staging map: thread t -> phys slot p=t&7 of rows rb, rb+32;
  // global source uses logical slot p ^ (rb&7) (pre-swizzled, rule #21)
  const int rb = t >> 3;                 // 0..31
  const int lsl = (t & 7) ^ (rb & 7);

  #define LDSRD(base, row, slot) \
    __builtin_bit_cast(f16x8, *(const u32x4*)&(base)[(row) * 32 + ((((slot) ^ ((row) & 7))) * 4)])

  #define GLOAD(dst, stg) do { \
    dst[0] = *(const u32x4*)(kfb + (size_t)((stg) * 64 + rb) * 2048 + lsl * 8); \
    dst[1] = *(const u32x4*)(kfb + (size_t)((stg) * 64 + rb + 32) * 2048 + lsl * 8); \
    dst[2] = *(const u32x4*)(vtb + (size_t)rb * 2048 + (stg) * 64 + lsl * 8); \
    dst[3] = *(const u32x4*)(vtb + (size_t)(rb + 32) * 2048 + (stg) * 64 + lsl * 8); \
  } while (0)

  // linear lane-contiguous 16B writes -> zero bank conflicts
  #define SWRITE(src, buf) do { \
    *(u32x4*)&S_k[(buf) * 2048 + t * 4]        = src[0]; \
    *(u32x4*)&S_k[(buf) * 2048 + 1024 + t * 4] = src[1]; \
    *(u32x4*)&S_v[(buf) * 2048 + t * 4]        = src[2]; \
    *(u32x4*)&S_v[(buf) * 2048 + 1024 + t * 4] = src[3]; \
  } while (0)

  u32x4 rg[3][4];                        // slot i%3 holds load L(i)
  f32x4 bias[2];
  unsigned psc0[32], psc1[32];
  float lsum = 0.f;
  f32x4 oacc[4] = {};

  // prologue: L0 -> LDS0 (through rg[0]); L1 -> rg[1]; L2 -> rg[2]
  GLOAD(rg[0], 0);
  SWRITE(rg[0], 0);
  GLOAD(rg[1], 1);
  GLOAD(rg[2], 2);
  {
    f32x4 b0 = *(const f32x4*)(pbRow + 4 * g);
    bias[0][0] = b0[0] - 8.f; bias[0][1] = b0[1] - 8.f;
    bias[0][2] = b0[2] - 8.f; bias[0][3] = b0[3] - 8.f;
  }
  __syncthreads();

  #pragma unroll
  for (int st = 0; st < 32; ++st) {
    const int cur = st & 1;              // compile-time under full unroll
    // slot st%3 was SWRITTEN at stage st-1 -> free for L(st+3)
    if (st < 29) GLOAD(rg[st % 3], st + 3);
    if (st < 31) {
      f32x4 bb = *(const f32x4*)(pbRow + (st + 1) * 64 + 4 * g);
      bias[cur ^ 1][0] = bb[0] - 8.f; bias[cur ^ 1][1] = bb[1] - 8.f;
      bias[cur ^ 1][2] = bb[2] - 8.f; bias[cur ^ 1][3] = bb[3] - 8.f;
    }

    // ---- QK: 2 MFMAs (dims 0-31, 32-63), independent chains ----
    {
      const int row = ct * 16 + c;
      const unsigned* kb = S_k + cur * 2048;
      f16x8 kfr0 = LDSRD(kb, row, g);
      f16x8 kfr1 = LDSRD(kb, row, 4 + g);
      f32x4 aA = {}, aB = {};
      aA = __builtin_amdgcn_mfma_f32_16x16x32_f16(kfr0, qfr0, aA, 0, 0, 0);
      aB = __builtin_amdgcn_mfma_f32_16x16x32_f16(kfr1, qfr1, aB, 0, 0, 0);
      float p0 = __expf(aA[0] + aB[0] + bias[cur][0]);
      float p1 = __expf(aA[1] + aB[1] + bias[cur][1]);
      float p2 = __expf(aA[2] + aB[2] + bias[cur][2]);
      float p3 = __expf(aA[3] + aB[3] + bias[cur][3]);
      lsum += (p0 + p1) + (p2 + p3);
      psc0[st] = pk_f16(p0, p1);
      psc1[st] = pk_f16(p2, p3);
    }

    // ---- PV: B from psc regs (fp16, K=16); A = V^T from LDS ----
    {
      u32x2 br; br[0] = psc0[st]; br[1] = psc1[st];
      const f16x4 bfrag = __builtin_bit_cast(f16x4, br);
      const unsigned* vb = S_v + cur * 2048;
      #pragma unroll
      for (int dt = 0; dt < 4; ++dt) {
        const int row = dt * 16 + c;
        const int sl = (2 * ct + (g >> 1)) ^ (row & 7);
        u32x2 ar = *(const u32x2*)&vb[row * 32 + sl * 4 + 2 * (g & 1)];
        f32x4 o = oacc[dt];
#if __has_builtin(__builtin_amdgcn_mfma_f32_16x16x16f16)
        o = __builtin_amdgcn_mfma_f32_16x16x16f16(__builtin_bit_cast(f16x4, ar), bfrag, o, 0, 0, 0);
#else
        asm("v_mfma_f32_16x16x16_f16 %0, %1, %2, %0" : "+v"(o) : "v"(__builtin_bit_cast(f16x4, ar)), "v"(bfrag));
#endif
        oacc[dt] = o;
      }
    }

    // ---- SWRITE L(st+1) (loaded at stage st-2; counted vmcnt) ----
    if (st < 31) SWRITE(rg[(st + 1) % 3], cur ^ 1);
    __syncthreads();
  }

  // ---- softmax denominator ----
  lsum += __shfl_xor(lsum, 16, 64);
  lsum += __shfl_xor(lsum, 32, 64);
  if (l < 16) lds_red[wid][l] = lsum;
  __syncthreads();
  const float inv = 1.0f / ((lds_red[0][c] + lds_red[1][c]) + (lds_red[2][c] + lds_red[3][c]));

  // ---- cross-wave out reduce (aliases staging LDS, stride 68) ----
  float* ored = (float*)smem;            // [4 waves][16 q][68]
  #pragma unroll
  for (int dt = 0; dt < 4; ++dt) {
    f32x4 o = oacc[dt];
    o[0] *= inv; o[1] *= inv; o[2] *= inv; o[3] *= inv;
    *(f32x4*)&ored[(wid * 16 + c) * 68 + dt * 16 + 4 * g] = o;
  }
  __syncthreads();
  {
    const int q = t >> 4;
    const int d0 = (t & 15) * 4;
    f32x4 s0 = *(const f32x4*)&ored[(0 * 16 + q) * 68 + d0];
    f32x4 s1 = *(const f32x4*)&ored[(1 * 16 + q) * 68 + d0];
    f32x4 s2 = *(const f32x4*)&ored[(2 * 16 + q) * 68 + d0];
    f32x4 s3 = *(const f32x4*)&ored[(3 * 16 + q) * 68 + d0];
    f32x4 s;
    s[0] = (s0[0] + s1[0]) + (s2[0] + s3[0]);
    s[1] = (s0[1] + s1[1]) + (s2[1] + s3[1]);
    s[2] = (s0[2] + s1[2]) + (s2[2] + s3[2]);
    s[3] = (s0[3] + s1[3]) + (s2[3] + s3[3]);
    u32x2 pk;
    pk[0] = pk_f16(s[0], s[1]);
    pk[1] = pk_f16(s[2], s[3]);
    *(u32x2*)&oc[((size_t)(qt * 16 + q) * 2 + b) * 1024 + h * 64 + d0] = pk;
  }

  // ---- attn write (normalized), unpack fp16 p ----
  float* arow = attn + ((size_t)(b * 16 + h) * S_ + qt * 16 + c) * S_ + ct * 16;
  #pragma unroll
  for (int st = 0; st < 32; ++st) {
    f16x2 h0 = __builtin_bit_cast(f16x2, psc0[st]);
    f16x2 h1 = __builtin_bit_cast(f16x2, psc1[st]);
    f32x4 o;
    o[0] = (float)h0[0] * inv;
    o[1] = (float)h0[1] * inv;
    o[2] = (float)h1[0] * inv;
    o[3] = (float)h1[1] * inv;
    *(f32x4*)(arow + (size_t)st * 64 + 4 * g) = o;
  }
  #undef LDSRD
  #undef GLOAD
  #undef SWRITE
}

// ---------------- out projection (fp16) ----------------
__launch_bounds__(256, 2)
__global__ void k_outproj(const unsigned short* __restrict__ oc, const unsigned short* __restrict__ ow,
                          const float* __restrict__ ob, float* __restrict__ out) {
  __shared__ unsigned short sA[128][40], sB[128][40];
  const int t = threadIdx.x;
  const int wid = t >> 6, l = t & 63, g = l >> 4, c = l & 15;
  const int wr = wid >> 1, wc = wid & 1;
  const int mb = blockIdx.x * 128, nb = blockIdx.y * 128;
  const int sr = t >> 1, sc = (t & 1) * 16;

  f32x4 acc[4][4] = {};
  for (int k0 = 0; k0 < 1024; k0 += 32) {
    __syncthreads();
    {
      const unsigned short* pa = oc + (size_t)(mb + sr) * 1024 + k0 + sc;
      const unsigned short* pb = ow + (size_t)(nb + sr) * 1024 + k0 + sc;
      *(f16x8*)&sA[sr][sc]     = *(const f16x8*)pa;
      *(f16x8*)&sA[sr][sc + 8] = *(const f16x8*)(pa + 8);
      *(f16x8*)&sB[sr][sc]     = *(const f16x8*)pb;
      *(f16x8*)&sB[sr][sc + 8] = *(const f16x8*)(pb + 8);
    }
    __syncthreads();
    f16x8 af[4], bf[4];
    #pragma unroll
    for (int i = 0; i < 4; ++i) {
      af[i] = *(const f16x8*)&sA[wr * 64 + i * 16 + c][g * 8];
      bf[i] = *(const f16x8*)&sB[wc * 64 + i * 16 + c][g * 8];
    }
    #pragma unroll
    for (int i = 0; i < 4; ++i)
      #pragma unroll
      for (int j = 0; j < 4; ++j)
        acc[i][j] = __builtin_amdgcn_mfma_f32_16x16x32_f16(af[i], bf[j], acc[i][j], 0, 0, 0);
  }
  #pragma unroll
  for (int i = 0; i < 4; ++i)
    #pragma unroll
    for (int j = 0; j < 4; ++j)
      #pragma unroll
      for (int rr = 0; rr < 4; ++rr) {
        int m = mb + wr * 64 + i * 16 + 4 * g + rr;
        int n = nb + wc * 64 + j * 16 + c;
        out[(size_t)m * 1024 + n] = acc[i][j][rr] + ob[n];
      }
}

extern "C" void kernel_launch(void* const* d_in, const int* in_sizes, int n_in,
                              void* d_out, int out_size, void* d_ws, size_t ws_size,
                              hipStream_t stream) {
  (void)in_sizes; (void)n_in; (void)out_size; (void)ws_size;
  const float* query = (const float*)d_in[0];
  const float* keyi  = (const float*)d_in[1];
  const float* value = (const float*)d_in[2];
  const float* posb  = (const float*)d_in[3];
  const float* ipw   = (const float*)d_in[4];
  const float* ipb   = (const float*)d_in[5];
  const float* outw  = (const float*)d_in[6];
  const float* outb  = (const float*)d_in[7];
  float* out = (float*)d_out;
  float* attn = out + (size_t)S_ * B_ * E_;

  char* ws = (char*)d_ws;
  size_t off = 0;
  auto alloc = [&](size_t bytes) -> void* {
    void* p = ws + off;
    off += (bytes + 255) & ~(size_t)255;
    return p;
  };
  const size_t NTOK = (size_t)S_ * B_;  // 4096
  unsigned short* qx  = (unsigned short*)alloc(NTOK * 1024 * 2);
  unsigned short* kx  = (unsigned short*)alloc(NTOK * 1024 * 2);
  unsigned short* vx  = (unsigned short*)alloc(NTOK * 1024 * 2);
  unsigned short* wqk = (unsigned short*)alloc((size_t)2048 * 1024 * 2);
  unsigned short* wv  = (unsigned short*)alloc((size_t)1024 * 1024 * 2);
  unsigned short* ow  = (unsigned short*)alloc((size_t)1024 * 1024 * 2);
  unsigned short* qf  = (unsigned short*)alloc(NTOK * 1024 * 2);
  unsigned short* kf  = (unsigned short*)alloc(NTOK * 1024 * 2);
  unsigned short* VT  = (unsigned short*)alloc((size_t)2 * 1024 * 2048 * 2);
  unsigned short* oc  = (unsigned short*)alloc(NTOK * 1024 * 2);

  const int n1_4 = (int)(NTOK * 1024 / 4);
  k_cvth<<<2048, 256, 0, stream>>>(query, qx, n1_4);
  k_cvth<<<2048, 256, 0, stream>>>(keyi, kx, n1_4);
  k_cvth<<<2048, 256, 0, stream>>>(value, vx, n1_4);
  k_cvth<<<1024, 256, 0, stream>>>(ipw, wqk, 2048 * 1024 / 4);
  k_cvth<<<512, 256, 0, stream>>>(ipw + 2048 * 1024, wv, 1024 * 1024 / 4);
  k_cvth<<<512, 256, 0, stream>>>(outw, ow, 1024 * 1024 / 4);

  k_proj_qk<<<dim3(32, 8, 2), 256, 0, stream>>>(qx, kx, wqk, ipb, qf, kf);
  k_proj_v<<<dim3(8, 32), 256, 0, stream>>>(wv, vx, ipb, VT);
  k_attn_pv<<<4096, 256, 0, stream>>>(qf, kf, VT, posb, attn, oc);
  k_outproj<<<dim3(32, 8), 256, 0, stream>>>(oc, ow, outb, out);
}